// Round 1
// baseline (762.366 us; speedup 1.0000x reference)
//
#include <hip/hip_runtime.h>
#include <stdint.h>

#define DEVFN __device__ __forceinline__

typedef unsigned short u16;
typedef unsigned int u32;

using f32x4 = __attribute__((ext_vector_type(4))) float;
using bfv8  = __attribute__((ext_vector_type(8))) short;   // 8 bf16 = 4 VGPR

#define CSC 0.12751745f   // (1/sqrt(128)) * log2(e)  -- folded into Q

DEVFN u16 f2bf(float f){
  u32 u = __float_as_uint(f);
  u32 r = u + 0x7FFFu + ((u >> 16) & 1u);
  return (u16)(r >> 16);
}
DEVFN float bf2f(u16 h){ return __uint_as_float(((u32)h) << 16); }

DEVFN void llds16(const void* g, void* l){
  __builtin_amdgcn_global_load_lds((const __attribute__((address_space(1))) void*)g,
                                   (__attribute__((address_space(3))) void*)l, 16, 0, 0);
}

DEVFN bfv8 as_bf(uint4 v){ return __builtin_bit_cast(bfv8, v); }

template<int C> DEVFN float dppf(float x){
  return __int_as_float(__builtin_amdgcn_update_dpp(0, __float_as_int(x), C, 0xf, 0xf, true));
}
// reduce across each 16-lane row via DPP (xor-masks {1,2,7,15} generate the full 16-group)
DEVFN float rmax16(float x){
  x = fmaxf(x, dppf<0xB1>(x));   // quad_perm [1,0,3,2]  (^1)
  x = fmaxf(x, dppf<0x4E>(x));   // quad_perm [2,3,0,1]  (^2)
  x = fmaxf(x, dppf<0x141>(x));  // row_half_mirror      (^7)
  x = fmaxf(x, dppf<0x140>(x));  // row_mirror           (^15)
  return x;
}
DEVFN float rsum16(float x){
  x += dppf<0xB1>(x);
  x += dppf<0x4E>(x);
  x += dppf<0x141>(x);
  x += dppf<0x140>(x);
  return x;
}

// ---------------- cast hidden fp32 -> bf16 ----------------
__global__ __launch_bounds__(256) void cvt_hid_kernel(const float* __restrict__ src, u16* __restrict__ dst){
  int i = blockIdx.x * 256 + threadIdx.x;           // 8 elems per thread
  const float* s = src + (size_t)i * 8;
  float4 a = *(const float4*)s;
  float4 b = *(const float4*)(s + 4);
  u16 t[8] = {f2bf(a.x), f2bf(a.y), f2bf(a.z), f2bf(a.w),
              f2bf(b.x), f2bf(b.y), f2bf(b.z), f2bf(b.w)};
  *(uint4*)(dst + (size_t)i * 8) = *(const uint4*)t;
}

// ---------------- weights: fp32 [K][N] -> bf16 B^T [N][K] (K=4096) ----------------
__global__ __launch_bounds__(256) void wtrans_kernel(const float* __restrict__ qw, const float* __restrict__ kw,
                                                     const float* __restrict__ vw, const float* __restrict__ ow,
                                                     u16* __restrict__ wtall, u16* __restrict__ wto){
  __shared__ float tile[64 * 65];
  int z = blockIdx.x, tid = threadIdx.x;
  const float* W; u16* WT; int Ndim; int rz;
  if (z < 4096)      { W = qw; WT = wtall;                         Ndim = 4096; rz = z; }
  else if (z < 5120) { W = kw; WT = wtall + (size_t)4096 * 4096;   Ndim = 1024; rz = z - 4096; }
  else if (z < 6144) { W = vw; WT = wtall + (size_t)5120 * 4096;   Ndim = 1024; rz = z - 5120; }
  else               { W = ow; WT = wto;                           Ndim = 4096; rz = z - 6144; }
  int ntn = Ndim >> 6;
  int tk = rz / ntn, tn = rz % ntn;
  const float* src = W + (size_t)(tk * 64) * Ndim + tn * 64;
  #pragma unroll
  for (int it = 0; it < 4; ++it){
    int fi = tid + it * 256;          // float4 index (1024 total)
    int r = fi >> 4, c4 = (fi & 15) * 4;
    float4 v = *(const float4*)(src + (size_t)r * Ndim + c4);
    tile[r * 65 + c4 + 0] = v.x; tile[r * 65 + c4 + 1] = v.y;
    tile[r * 65 + c4 + 2] = v.z; tile[r * 65 + c4 + 3] = v.w;
  }
  __syncthreads();
  u16* dst = WT + (size_t)(tn * 64) * 4096 + tk * 64;
  #pragma unroll
  for (int it = 0; it < 2; ++it){
    int ci = tid + it * 256;          // chunk of 8 (512 total)
    int n = ci >> 3, k8 = (ci & 7) * 8;
    u16 tmp[8];
    #pragma unroll
    for (int j = 0; j < 8; ++j) tmp[j] = f2bf(tile[(k8 + j) * 65 + n]);
    *(uint4*)(dst + (size_t)n * 4096 + k8) = *(const uint4*)tmp;
  }
}

// ---------------- m97-style bf16 GEMM: C[M,N] = A[M,4096] * (BT[N,4096])^T ----------------
template<int OUTF32>
__global__ __launch_bounds__(256) void gemm_kernel(const u16* __restrict__ A, const u16* __restrict__ BT,
                                                   void* __restrict__ Cv, int N, int ntn){
  constexpr int K = 4096;
  __shared__ u16 As[2][128 * 32];
  __shared__ u16 Bs[2][128 * 32];
  int bid = blockIdx.x;
  int bm = bid / ntn, bn = bid % ntn;
  int tid = threadIdx.x, lane = tid & 63, w = tid >> 6;
  int wr = w >> 1, wc = w & 1;
  int l15 = lane & 15, lh = lane >> 4;
  const u16* Ab = A  + (size_t)(bm * 128) * K;
  const u16* Bb = BT + (size_t)(bn * 128) * K;
  f32x4 acc[4][4];
  #pragma unroll
  for (int m = 0; m < 4; ++m)
    #pragma unroll
    for (int n = 0; n < 4; ++n) acc[m][n] = f32x4{0.f, 0.f, 0.f, 0.f};

  auto stage = [&](int buf, int k0){
    #pragma unroll
    for (int p = 0; p < 2; ++p){
      int cid = tid + p * 256;
      int row = cid >> 2, k8 = (cid & 3) * 8;
      llds16(Ab + (size_t)row * K + k0 + k8, (char*)(&As[buf][0]) + p * 4096 + w * 1024);
      llds16(Bb + (size_t)row * K + k0 + k8, (char*)(&Bs[buf][0]) + p * 4096 + w * 1024);
    }
  };
  stage(0, 0);
  __syncthreads();
  for (int kt = 0; kt < K / 32; ++kt){
    int cur = kt & 1;
    if (kt + 1 < K / 32) stage(cur ^ 1, (kt + 1) * 32);
    uint4 af[4], bfr[4];
    #pragma unroll
    for (int i = 0; i < 4; ++i){
      af[i]  = *(const uint4*)(&As[cur][(wr * 64 + i * 16 + l15) * 32 + lh * 8]);
      bfr[i] = *(const uint4*)(&Bs[cur][(wc * 64 + i * 16 + l15) * 32 + lh * 8]);
    }
    #pragma unroll
    for (int m = 0; m < 4; ++m)
      #pragma unroll
      for (int n = 0; n < 4; ++n)
        acc[m][n] = __builtin_amdgcn_mfma_f32_16x16x32_bf16(as_bf(af[m]), as_bf(bfr[n]), acc[m][n], 0, 0, 0);
    __syncthreads();
  }
  int row0 = bm * 128 + wr * 64, col0 = bn * 128 + wc * 64;
  if (OUTF32){
    float* C = (float*)Cv;
    #pragma unroll
    for (int m = 0; m < 4; ++m)
      #pragma unroll
      for (int n = 0; n < 4; ++n)
        #pragma unroll
        for (int r = 0; r < 4; ++r)
          C[(size_t)(row0 + m * 16 + lh * 4 + r) * N + col0 + n * 16 + l15] = acc[m][n][r];
  } else {
    u16* C = (u16*)Cv;
    #pragma unroll
    for (int m = 0; m < 4; ++m)
      #pragma unroll
      for (int n = 0; n < 4; ++n)
        #pragma unroll
        for (int r = 0; r < 4; ++r)
          C[(size_t)(row0 + m * 16 + lh * 4 + r) * N + col0 + n * 16 + l15] = f2bf(acc[m][n][r]);
  }
}

// ---------------- RoPE: Q (scaled by CSC) -> qrope ; K -> kimg tile 63 ----------------
__global__ __launch_bounds__(256) void rope_kernel(const u16* __restrict__ qkvp, u16* __restrict__ qrope,
                                                   u16* __restrict__ kimg){
  int z = blockIdx.x, tid = threadIdx.x;
  if (z < 512){
    int b = z >> 5, h = z & 31;
    for (int it = 0; it < 16; ++it){
      int i = tid + it * 256;
      int s = i >> 6, j = i & 63;
      const u16* src = qkvp + (size_t)(b * 64 + s) * 6144 + h * 128;
      float q0 = bf2f(src[j]), q1 = bf2f(src[j + 64]);
      float inv = expf(-(float)j * 0.14391157f);      // 1/10000^(j/64)
      float ang = (4032.0f + (float)s) * inv;
      float sn = sinf(ang), cs = cosf(ang);
      u16* dst = qrope + (size_t)((b * 32 + h) * 64 + s) * 128;
      dst[j]      = f2bf((q0 * cs - q1 * sn) * CSC);
      dst[j + 64] = f2bf((q1 * cs + q0 * sn) * CSC);
    }
  } else {
    int z2 = z - 512, b = z2 >> 3, kvh = z2 & 7;
    for (int it = 0; it < 16; ++it){
      int i = tid + it * 256;
      int s = i >> 6, j = i & 63;
      const u16* src = qkvp + (size_t)(b * 64 + s) * 6144 + 4096 + kvh * 128;
      float q0 = bf2f(src[j]), q1 = bf2f(src[j + 64]);
      float inv = expf(-(float)j * 0.14391157f);
      float ang = (4032.0f + (float)s) * inv;
      float sn = sinf(ang), cs = cosf(ang);
      u16* dst = kimg + (size_t)((b * 8 + kvh) * 64 + 63) * 8192;   // tile 63 = new keys
      float v0 = q0 * cs - q1 * sn, v1 = q1 * cs + q0 * sn;
      int dc0 = j >> 3, dc1 = (j + 64) >> 3;
      dst[s * 128 + (((dc0 & 8) | ((dc0 ^ s) & 7)) * 8) + (j & 7)]        = f2bf(v0);
      dst[s * 128 + (((dc1 & 8) | ((dc1 ^ s) & 7)) * 8) + ((j + 64) & 7)] = f2bf(v1);
    }
  }
}

// ---------------- KV-cache image build: beam gather + cast + swizzle (+ V transpose) ----------------
__global__ __launch_bounds__(256) void imgbuild_kernel(const float* __restrict__ pastk, const float* __restrict__ pastv,
                                                       const u16* __restrict__ qkvp, const int* __restrict__ beam,
                                                       u16* __restrict__ kimg, u16* __restrict__ vimg){
  __shared__ float T[64 * 129];
  int z = blockIdx.x, tid = threadIdx.x;
  if (z < 8064){                                 // K tiles 0..62 for (b,kv)
    int b = z / 504, r = z % 504, kv = r / 63, tile = r % 63;
    const float* src = pastk + ((size_t)(beam[b] * 8 + kv) * 4032 + tile * 64) * 128;
    u16* dst = kimg + (size_t)((b * 8 + kv) * 64 + tile) * 8192;
    #pragma unroll
    for (int it = 0; it < 4; ++it){
      int i = tid + it * 256;                    // chunk id (1024 total)
      int t = i >> 4, dc = i & 15;
      const float* s8 = src + t * 128 + dc * 8;
      float4 a = *(const float4*)s8;
      float4 c = *(const float4*)(s8 + 4);
      u16 tmp[8] = {f2bf(a.x), f2bf(a.y), f2bf(a.z), f2bf(a.w),
                    f2bf(c.x), f2bf(c.y), f2bf(c.z), f2bf(c.w)};
      int dcs = (dc & 8) | ((dc ^ t) & 7);
      *(uint4*)(dst + t * 128 + dcs * 8) = *(const uint4*)tmp;
    }
  } else {                                       // V tiles 0..63, transposed to [d][t]
    int z2 = z - 8064;
    int b = z2 / 512, r = z2 % 512, kv = r / 64, tile = r % 64;
    if (tile < 63){
      const float* src = pastv + ((size_t)(beam[b] * 8 + kv) * 4032 + tile * 64) * 128;
      #pragma unroll
      for (int it = 0; it < 4; ++it){
        int i = tid + it * 256;
        int t = i >> 4, d0 = (i & 15) * 8;
        const float* s8 = src + t * 128 + d0;
        float4 a = *(const float4*)s8;
        float4 c = *(const float4*)(s8 + 4);
        float vv[8] = {a.x, a.y, a.z, a.w, c.x, c.y, c.z, c.w};
        #pragma unroll
        for (int j = 0; j < 8; ++j) T[t * 129 + d0 + j] = vv[j];
      }
    } else {
      #pragma unroll
      for (int it = 0; it < 4; ++it){
        int i = tid + it * 256;
        int t = i >> 4, d0 = (i & 15) * 8;
        uint4 raw = *(const uint4*)(qkvp + (size_t)(b * 64 + t) * 6144 + 5120 + kv * 128 + d0);
        u16 tmp[8]; *(uint4*)tmp = raw;
        #pragma unroll
        for (int j = 0; j < 8; ++j) T[t * 129 + d0 + j] = bf2f(tmp[j]);
      }
    }
    __syncthreads();
    u16* dst = vimg + (size_t)((b * 8 + kv) * 64 + tile) * 8192;
    #pragma unroll
    for (int it = 0; it < 4; ++it){
      int ci = tid + it * 256;                   // output chunk (1024 total)
      int d = ci >> 3, tc = ci & 7;
      u16 tmp[8];
      #pragma unroll
      for (int k = 0; k < 8; ++k) tmp[k] = f2bf(T[(tc * 8 + k) * 129 + d]);
      *(uint4*)(dst + d * 64 + ((tc ^ (d & 7)) * 8)) = *(const uint4*)tmp;
    }
  }
}

// ---------------- flash attention over one T-chunk of 1024 ----------------
__global__ __launch_bounds__(256, 1) void attn_kernel(const u16* __restrict__ qrope, const u16* __restrict__ kimg,
                                                      const u16* __restrict__ vimg, float* __restrict__ pctx,
                                                      float* __restrict__ pm, float* __restrict__ pl){
  extern __shared__ char smem[];
  u16* Ks = (u16*)smem;                 // [2][64*128]
  u16* Vs = (u16*)(smem + 32768);       // [2][64*128]
  u16* Ps = (u16*)(smem + 65536);       // [4][64*64]
  int kv = blockIdx.x, b = blockIdx.y, chunk = blockIdx.z;
  int tid = threadIdx.x, lane = tid & 63, g = tid >> 6;
  int l15 = lane & 15, lh = lane >> 4;

  // Q fragments resident in registers (pre-scaled by CSC in rope)
  const u16* qb = qrope + (size_t)((b * 32 + kv * 4 + g) * 64) * 128;
  uint4 qf[4][4];
  #pragma unroll
  for (int m = 0; m < 4; ++m)
    #pragma unroll
    for (int ks = 0; ks < 4; ++ks)
      qf[m][ks] = *(const uint4*)(qb + (size_t)(m * 16 + l15) * 128 + ks * 32 + lh * 8);

  f32x4 cacc[4][8], mrow[4], lrow[4];
  #pragma unroll
  for (int m = 0; m < 4; ++m){
    mrow[m] = f32x4{-3.0e38f, -3.0e38f, -3.0e38f, -3.0e38f};
    lrow[m] = f32x4{0.f, 0.f, 0.f, 0.f};
    #pragma unroll
    for (int nd = 0; nd < 8; ++nd) cacc[m][nd] = f32x4{0.f, 0.f, 0.f, 0.f};
  }

  const u16* kbase = kimg + (size_t)((b * 8 + kv) * 64 + chunk * 16) * 8192;
  const u16* vbase = vimg + (size_t)((b * 8 + kv) * 64 + chunk * 16) * 8192;

  auto stageKV = [&](int buf, int tile){
    const u16* kt = kbase + (size_t)tile * 8192;
    const u16* vt = vbase + (size_t)tile * 8192;
    #pragma unroll
    for (int p = 0; p < 4; ++p){
      llds16((const char*)kt + p * 4096 + tid * 16, (char*)Ks + buf * 16384 + p * 4096 + g * 1024);
      llds16((const char*)vt + p * 4096 + tid * 16, (char*)Vs + buf * 16384 + p * 4096 + g * 1024);
    }
  };
  stageKV(0, 0);
  __syncthreads();

  for (int it = 0; it < 16; ++it){
    int cur = it & 1;
    if (it < 15) stageKV(cur ^ 1, it + 1);

    // S = Q * K^T
    const u16* Kc = Ks + cur * 8192;
    f32x4 sacc[4][4];
    #pragma unroll
    for (int m = 0; m < 4; ++m)
      #pragma unroll
      for (int nt = 0; nt < 4; ++nt) sacc[m][nt] = f32x4{0.f, 0.f, 0.f, 0.f};
    #pragma unroll
    for (int ks = 0; ks < 4; ++ks){
      #pragma unroll
      for (int nt = 0; nt < 4; ++nt){
        int t = nt * 16 + l15;
        int dc = ks * 4 + lh;
        int dcs = (dc & 8) | ((dc ^ t) & 7);
        uint4 kf = *(const uint4*)(Kc + t * 128 + dcs * 8);
        #pragma unroll
        for (int m = 0; m < 4; ++m)
          sacc[m][nt] = __builtin_amdgcn_mfma_f32_16x16x32_bf16(as_bf(qf[m][ks]), as_bf(kf), sacc[m][nt], 0, 0, 0);
      }
    }
    // causal mask only in the very last global tile (t_local > s_row)
    if (chunk == 3 && it == 15){
      #pragma unroll
      for (int m = 0; m < 4; ++m)
        #pragma unroll
        for (int nt = 0; nt < 4; ++nt)
          #pragma unroll
          for (int r = 0; r < 4; ++r){
            int srow = m * 16 + lh * 4 + r;
            int tl = nt * 16 + l15;
            if (tl > srow) sacc[m][nt][r] = -3.0e38f;
          }
    }
    // online softmax (scores already in exp2 units)
    #pragma unroll
    for (int m = 0; m < 4; ++m){
      f32x4 mnew, esc, rs;
      #pragma unroll
      for (int r = 0; r < 4; ++r){
        float rm = fmaxf(fmaxf(sacc[m][0][r], sacc[m][1][r]), fmaxf(sacc[m][2][r], sacc[m][3][r]));
        rm = rmax16(rm);
        float mn = fmaxf(mrow[m][r], rm);
        mnew[r] = mn;
        esc[r] = exp2f(mrow[m][r] - mn);
      }
      mrow[m] = mnew;
      #pragma unroll
      for (int r = 0; r < 4; ++r){
        float a = 0.f;
        #pragma unroll
        for (int nt = 0; nt < 4; ++nt){
          float pv = exp2f(sacc[m][nt][r] - mnew[r]);
          sacc[m][nt][r] = pv;
          a += pv;
        }
        rs[r] = rsum16(a);
      }
      #pragma unroll
      for (int r = 0; r < 4; ++r) lrow[m][r] = lrow[m][r] * esc[r] + rs[r];
      #pragma unroll
      for (int nd = 0; nd < 8; ++nd) cacc[m][nd] *= esc;
      // P -> per-wave swizzled LDS buffer ([q][t], chunk XOR q&7)
      u16* Pw = Ps + g * 4096;
      #pragma unroll
      for (int nt = 0; nt < 4; ++nt)
        #pragma unroll
        for (int r = 0; r < 4; ++r){
          int q = m * 16 + lh * 4 + r;
          int t = nt * 16 + l15;
          Pw[q * 64 + (((t >> 3) ^ (q & 7)) * 8) + (t & 7)] = f2bf(sacc[m][nt][r]);
        }
    }
    // ctx += P * V
    const u16* Vc = Vs + cur * 8192;
    #pragma unroll
    for (int ks = 0; ks < 2; ++ks){
      uint4 pf[4];
      #pragma unroll
      for (int m = 0; m < 4; ++m){
        int q = m * 16 + l15;
        pf[m] = *(const uint4*)(Ps + g * 4096 + q * 64 + (((ks * 4 + lh) ^ (q & 7)) * 8));
      }
      #pragma unroll
      for (int nd = 0; nd < 8; ++nd){
        int d = nd * 16 + l15;
        uint4 vf = *(const uint4*)(Vc + d * 64 + (((ks * 4 + lh) ^ (d & 7)) * 8));
        #pragma unroll
        for (int m = 0; m < 4; ++m)
          cacc[m][nd] = __builtin_amdgcn_mfma_f32_16x16x32_bf16(as_bf(pf[m]), as_bf(vf), cacc[m][nd], 0, 0, 0);
      }
    }
    __syncthreads();
  }

  // write unnormalized partials + (m,l)
  float* pc = pctx + (size_t)(((chunk * 16 + b) * 8 + kv) * 4 + g) * 8192;
  #pragma unroll
  for (int m = 0; m < 4; ++m)
    #pragma unroll
    for (int nd = 0; nd < 8; ++nd)
      #pragma unroll
      for (int r = 0; r < 4; ++r)
        pc[(m * 16 + lh * 4 + r) * 128 + nd * 16 + l15] = cacc[m][nd][r];
  if (l15 == 0){
    size_t mb = (size_t)((chunk * 16 + b) * 8 + kv) * 256 + g * 64;
    #pragma unroll
    for (int m = 0; m < 4; ++m)
      #pragma unroll
      for (int r = 0; r < 4; ++r){
        pm[mb + m * 16 + lh * 4 + r] = mrow[m][r];
        pl[mb + m * 16 + lh * 4 + r] = lrow[m][r];
      }
  }
}

// ---------------- combine the 4 chunk partials ----------------
__global__ __launch_bounds__(256) void combine_kernel(const float* __restrict__ pctx, const float* __restrict__ pm,
                                                      const float* __restrict__ pl, u16* __restrict__ ctxb){
  int z = blockIdx.x;
  int g = z & 3, kv = (z >> 2) & 7, b = z >> 5;
  int tid = threadIdx.x;
  int s = tid >> 2, dq = (tid & 3) * 32;
  float mv[4], lv[4];
  #pragma unroll
  for (int c = 0; c < 4; ++c){
    size_t mi = (size_t)((c * 16 + b) * 8 + kv) * 256 + g * 64 + s;
    mv[c] = pm[mi]; lv[c] = pl[mi];
  }
  float M = fmaxf(fmaxf(mv[0], mv[1]), fmaxf(mv[2], mv[3]));
  float wc[4], wsum = 0.f;
  #pragma unroll
  for (int c = 0; c < 4; ++c){ wc[c] = exp2f(mv[c] - M); wsum += wc[c] * lv[c]; }
  float inv = 1.0f / wsum;
  u16* dst = ctxb + (size_t)(b * 64 + s) * 4096 + (kv * 4 + g) * 128 + dq;
  #pragma unroll
  for (int j4 = 0; j4 < 8; ++j4){
    float4 a = {0.f, 0.f, 0.f, 0.f};
    #pragma unroll
    for (int c = 0; c < 4; ++c){
      const float* p = pctx + (size_t)(((c * 16 + b) * 8 + kv) * 4 + g) * 8192 + s * 128 + dq + j4 * 4;
      float4 v = *(const float4*)p;
      a.x += wc[c] * v.x; a.y += wc[c] * v.y; a.z += wc[c] * v.z; a.w += wc[c] * v.w;
    }
    u16 t4[4] = {f2bf(a.x * inv), f2bf(a.y * inv), f2bf(a.z * inv), f2bf(a.w * inv)};
    *(uint2*)(dst + j4 * 4) = *(const uint2*)t4;
  }
}

extern "C" void kernel_launch(void* const* d_in, const int* in_sizes, int n_in,
                              void* d_out, int out_size, void* d_ws, size_t ws_size,
                              hipStream_t stream){
  const float* hidden = (const float*)d_in[0];
  const float* pastk  = (const float*)d_in[1];
  const float* pastv  = (const float*)d_in[2];
  const float* qw     = (const float*)d_in[3];
  const float* kw     = (const float*)d_in[4];
  const float* vw     = (const float*)d_in[5];
  const float* ow     = (const float*)d_in[6];
  const int*   beam   = (const int*)d_in[7];

  char* ws = (char*)d_ws;
  size_t off = 0;
  auto alloc = [&](size_t sz){ char* p = ws + off; off += sz; return p; };
  u16*   wtall = (u16*)alloc(50331648);     // [6144][4096] bf16: q,k,v weights transposed
  u16*   wto   = (u16*)alloc(33554432);     // [4096][4096] bf16: out_wei transposed
  u16*   hidb  = (u16*)alloc(8388608);      // hidden bf16 [1024][4096]
  u16*   qkvp  = (u16*)alloc(12582912);     // QKV proj [1024][6144]
  u16*   qrope = (u16*)alloc(8388608);      // [16][32][64][128]
  u16*   kimg  = (u16*)alloc(134217728);    // [16][8][64 tiles][64x128 swz]
  u16*   vimg  = (u16*)alloc(134217728);    // [16][8][64 tiles][128x64 swz, transposed]
  float* pctx  = (float*)alloc(67108864);   // [4][16][8][4][64][128]
  float* pm    = (float*)alloc(524288);
  float* pl    = (float*)alloc(524288);
  u16*   ctxb  = (u16*)alloc(8388608);      // [1024][4096]
  if (off > ws_size) return;                // workspace too small -> fail loudly

  hipFuncSetAttribute((const void*)attn_kernel, hipFuncAttributeMaxDynamicSharedMemorySize, 98304);

  cvt_hid_kernel<<<2048, 256, 0, stream>>>(hidden, hidb);
  wtrans_kernel<<<10240, 256, 0, stream>>>(qw, kw, vw, ow, wtall, wto);
  gemm_kernel<0><<<384, 256, 0, stream>>>(hidb, wtall, (void*)qkvp, 6144, 48);
  rope_kernel<<<640, 256, 0, stream>>>(qkvp, qrope, kimg);
  imgbuild_kernel<<<16256, 256, 0, stream>>>(pastk, pastv, qkvp, beam, kimg, vimg);
  attn_kernel<<<dim3(8, 16, 4), 256, 98304, stream>>>(qrope, kimg, vimg, pctx, pm, pl);
  combine_kernel<<<512, 256, 0, stream>>>(pctx, pm, pl, ctxb);
  gemm_kernel<1><<<256, 256, 0, stream>>>(ctxb, wto, d_out, 4096, 32);
}

// Round 2
// 626.221 us; speedup vs baseline: 1.2174x; 1.2174x over previous
//
#include <hip/hip_runtime.h>
#include <stdint.h>

#define DEVFN __device__ __forceinline__

typedef unsigned short u16;
typedef unsigned int u32;

using f32x4 = __attribute__((ext_vector_type(4))) float;
using bfv8  = __attribute__((ext_vector_type(8))) short;   // 8 bf16 = 4 VGPR
using s16x4 = __attribute__((ext_vector_type(4))) short;   // 4 bf16 = 2 VGPR

#define CSC 0.12751745f   // (1/sqrt(128)) * log2(e)  -- folded into Q

DEVFN u16 f2bf(float f){
  u32 u = __float_as_uint(f);
  u32 r = u + 0x7FFFu + ((u >> 16) & 1u);
  return (u16)(r >> 16);
}
DEVFN float bf2f(u16 h){ return __uint_as_float(((u32)h) << 16); }

DEVFN void llds16(const void* g, void* l){
  __builtin_amdgcn_global_load_lds((const __attribute__((address_space(1))) void*)g,
                                   (__attribute__((address_space(3))) void*)l, 16, 0, 0);
}

DEVFN bfv8 as_bf(uint4 v){ return __builtin_bit_cast(bfv8, v); }

#if __has_builtin(__builtin_amdgcn_mfma_f32_16x16x16bf16_1k)
DEVFN f32x4 mfma16(s16x4 a, s16x4 b, f32x4 c){
  return __builtin_amdgcn_mfma_f32_16x16x16bf16_1k(a, b, c, 0, 0, 0);
}
#else
DEVFN f32x4 mfma16(s16x4 a, s16x4 b, f32x4 c){
  asm("v_mfma_f32_16x16x16_bf16 %0, %1, %2, %0" : "+v"(c) : "v"(a), "v"(b));
  return c;
}
#endif

DEVFN u32 cvtpk(float lo, float hi){
  u32 w;
  asm("v_cvt_pk_bf16_f32 %0, %1, %2" : "=v"(w) : "v"(lo), "v"(hi));
  return w;
}

// ---------------- cast hidden fp32 -> bf16 ----------------
__global__ __launch_bounds__(256) void cvt_hid_kernel(const float* __restrict__ src, u16* __restrict__ dst){
  int i = blockIdx.x * 256 + threadIdx.x;           // 8 elems per thread
  const float* s = src + (size_t)i * 8;
  float4 a = *(const float4*)s;
  float4 b = *(const float4*)(s + 4);
  u16 t[8] = {f2bf(a.x), f2bf(a.y), f2bf(a.z), f2bf(a.w),
              f2bf(b.x), f2bf(b.y), f2bf(b.z), f2bf(b.w)};
  *(uint4*)(dst + (size_t)i * 8) = *(const uint4*)t;
}

// ---------------- weights: fp32 [K][N] -> bf16 B^T [N][K] (K=4096) ----------------
__global__ __launch_bounds__(256) void wtrans_kernel(const float* __restrict__ qw, const float* __restrict__ kw,
                                                     const float* __restrict__ vw, const float* __restrict__ ow,
                                                     u16* __restrict__ wtall, u16* __restrict__ wto){
  __shared__ float tile[64 * 65];
  int z = blockIdx.x, tid = threadIdx.x;
  const float* W; u16* WT; int Ndim; int rz;
  if (z < 4096)      { W = qw; WT = wtall;                         Ndim = 4096; rz = z; }
  else if (z < 5120) { W = kw; WT = wtall + (size_t)4096 * 4096;   Ndim = 1024; rz = z - 4096; }
  else if (z < 6144) { W = vw; WT = wtall + (size_t)5120 * 4096;   Ndim = 1024; rz = z - 5120; }
  else               { W = ow; WT = wto;                           Ndim = 4096; rz = z - 6144; }
  int ntn = Ndim >> 6;
  int tk = rz / ntn, tn = rz % ntn;
  const float* src = W + (size_t)(tk * 64) * Ndim + tn * 64;
  #pragma unroll
  for (int it = 0; it < 4; ++it){
    int fi = tid + it * 256;          // float4 index (1024 total)
    int r = fi >> 4, c4 = (fi & 15) * 4;
    float4 v = *(const float4*)(src + (size_t)r * Ndim + c4);
    tile[r * 65 + c4 + 0] = v.x; tile[r * 65 + c4 + 1] = v.y;
    tile[r * 65 + c4 + 2] = v.z; tile[r * 65 + c4 + 3] = v.w;
  }
  __syncthreads();
  u16* dst = WT + (size_t)(tn * 64) * 4096 + tk * 64;
  #pragma unroll
  for (int it = 0; it < 2; ++it){
    int ci = tid + it * 256;          // chunk of 8 (512 total)
    int n = ci >> 3, k8 = (ci & 7) * 8;
    u16 tmp[8];
    #pragma unroll
    for (int j = 0; j < 8; ++j) tmp[j] = f2bf(tile[(k8 + j) * 65 + n]);
    *(uint4*)(dst + (size_t)n * 4096 + k8) = *(const uint4*)tmp;
  }
}

// ---------------- m97-style bf16 GEMM: C[M,N] = A[M,4096] * (BT[N,4096])^T ----------------
template<int OUTF32>
__global__ __launch_bounds__(256) void gemm_kernel(const u16* __restrict__ A, const u16* __restrict__ BT,
                                                   void* __restrict__ Cv, int N, int ntn){
  constexpr int K = 4096;
  __shared__ u16 As[2][128 * 32];
  __shared__ u16 Bs[2][128 * 32];
  int bid = blockIdx.x;
  int bm = bid / ntn, bn = bid % ntn;
  int tid = threadIdx.x, lane = tid & 63, w = tid >> 6;
  int wr = w >> 1, wc = w & 1;
  int l15 = lane & 15, lh = lane >> 4;
  const u16* Ab = A  + (size_t)(bm * 128) * K;
  const u16* Bb = BT + (size_t)(bn * 128) * K;
  f32x4 acc[4][4];
  #pragma unroll
  for (int m = 0; m < 4; ++m)
    #pragma unroll
    for (int n = 0; n < 4; ++n) acc[m][n] = f32x4{0.f, 0.f, 0.f, 0.f};

  auto stage = [&](int buf, int k0){
    #pragma unroll
    for (int p = 0; p < 2; ++p){
      int cid = tid + p * 256;
      int row = cid >> 2, k8 = (cid & 3) * 8;
      llds16(Ab + (size_t)row * K + k0 + k8, (char*)(&As[buf][0]) + p * 4096 + w * 1024);
      llds16(Bb + (size_t)row * K + k0 + k8, (char*)(&Bs[buf][0]) + p * 4096 + w * 1024);
    }
  };
  stage(0, 0);
  __syncthreads();
  for (int kt = 0; kt < K / 32; ++kt){
    int cur = kt & 1;
    if (kt + 1 < K / 32) stage(cur ^ 1, (kt + 1) * 32);
    uint4 af[4], bfr[4];
    #pragma unroll
    for (int i = 0; i < 4; ++i){
      af[i]  = *(const uint4*)(&As[cur][(wr * 64 + i * 16 + l15) * 32 + lh * 8]);
      bfr[i] = *(const uint4*)(&Bs[cur][(wc * 64 + i * 16 + l15) * 32 + lh * 8]);
    }
    #pragma unroll
    for (int m = 0; m < 4; ++m)
      #pragma unroll
      for (int n = 0; n < 4; ++n)
        acc[m][n] = __builtin_amdgcn_mfma_f32_16x16x32_bf16(as_bf(af[m]), as_bf(bfr[n]), acc[m][n], 0, 0, 0);
    __syncthreads();
  }
  int row0 = bm * 128 + wr * 64, col0 = bn * 128 + wc * 64;
  if (OUTF32){
    float* C = (float*)Cv;
    #pragma unroll
    for (int m = 0; m < 4; ++m)
      #pragma unroll
      for (int n = 0; n < 4; ++n)
        #pragma unroll
        for (int r = 0; r < 4; ++r)
          C[(size_t)(row0 + m * 16 + lh * 4 + r) * N + col0 + n * 16 + l15] = acc[m][n][r];
  } else {
    u16* C = (u16*)Cv;
    #pragma unroll
    for (int m = 0; m < 4; ++m)
      #pragma unroll
      for (int n = 0; n < 4; ++n)
        #pragma unroll
        for (int r = 0; r < 4; ++r)
          C[(size_t)(row0 + m * 16 + lh * 4 + r) * N + col0 + n * 16 + l15] = f2bf(acc[m][n][r]);
  }
}

// ---------------- RoPE: Q (scaled by CSC) -> qrope ; K -> kimg tile 63 ----------------
__global__ __launch_bounds__(256) void rope_kernel(const u16* __restrict__ qkvp, u16* __restrict__ qrope,
                                                   u16* __restrict__ kimg){
  int z = blockIdx.x, tid = threadIdx.x;
  if (z < 512){
    int b = z >> 5, h = z & 31;
    for (int it = 0; it < 16; ++it){
      int i = tid + it * 256;
      int s = i >> 6, j = i & 63;
      const u16* src = qkvp + (size_t)(b * 64 + s) * 6144 + h * 128;
      float q0 = bf2f(src[j]), q1 = bf2f(src[j + 64]);
      float inv = expf(-(float)j * 0.14391157f);      // 1/10000^(j/64)
      float ang = (4032.0f + (float)s) * inv;
      float sn = sinf(ang), cs = cosf(ang);
      u16* dst = qrope + (size_t)((b * 32 + h) * 64 + s) * 128;
      dst[j]      = f2bf((q0 * cs - q1 * sn) * CSC);
      dst[j + 64] = f2bf((q1 * cs + q0 * sn) * CSC);
    }
  } else {
    int z2 = z - 512, b = z2 >> 3, kvh = z2 & 7;
    for (int it = 0; it < 16; ++it){
      int i = tid + it * 256;
      int s = i >> 6, j = i & 63;
      const u16* src = qkvp + (size_t)(b * 64 + s) * 6144 + 4096 + kvh * 128;
      float q0 = bf2f(src[j]), q1 = bf2f(src[j + 64]);
      float inv = expf(-(float)j * 0.14391157f);
      float ang = (4032.0f + (float)s) * inv;
      float sn = sinf(ang), cs = cosf(ang);
      u16* dst = kimg + (size_t)((b * 8 + kvh) * 64 + 63) * 8192;   // 64t-tile 63 = new keys
      float v0 = q0 * cs - q1 * sn, v1 = q1 * cs + q0 * sn;
      int dc0 = j >> 3, dc1 = (j + 64) >> 3;
      dst[s * 128 + (((dc0 & 8) | ((dc0 ^ s) & 7)) * 8) + (j & 7)]        = f2bf(v0);
      dst[s * 128 + (((dc1 & 8) | ((dc1 ^ s) & 7)) * 8) + ((j + 64) & 7)] = f2bf(v1);
    }
  }
}

// ---------------- KV-cache image build: beam gather + cast + swizzle (+ V transpose) ----------------
// kimg: per (b,kv): 64 tiles of [64 t][128 d], d in 8-elem chunks, chunk swz (dc&8)|((dc^t)&7)
// vimg: per (b,kv): 128 tiles of [128 d][32 t], t in 4-elem chunks, chunk swz c^(d&7)
__global__ __launch_bounds__(256) void imgbuild_kernel(const float* __restrict__ pastk, const float* __restrict__ pastv,
                                                       const u16* __restrict__ qkvp, const int* __restrict__ beam,
                                                       u16* __restrict__ kimg, u16* __restrict__ vimg){
  __shared__ float T[64 * 129];
  int z = blockIdx.x, tid = threadIdx.x;
  if (z < 8064){                                 // K tiles 0..62 for (b,kv)
    int b = z / 504, r = z % 504, kv = r / 63, tile = r % 63;
    const float* src = pastk + ((size_t)(beam[b] * 8 + kv) * 4032 + tile * 64) * 128;
    u16* dst = kimg + (size_t)((b * 8 + kv) * 64 + tile) * 8192;
    #pragma unroll
    for (int it = 0; it < 4; ++it){
      int i = tid + it * 256;                    // chunk id (1024 total)
      int t = i >> 4, dc = i & 15;
      const float* s8 = src + t * 128 + dc * 8;
      float4 a = *(const float4*)s8;
      float4 c = *(const float4*)(s8 + 4);
      u16 tmp[8] = {f2bf(a.x), f2bf(a.y), f2bf(a.z), f2bf(a.w),
                    f2bf(c.x), f2bf(c.y), f2bf(c.z), f2bf(c.w)};
      int dcs = (dc & 8) | ((dc ^ t) & 7);
      *(uint4*)(dst + t * 128 + dcs * 8) = *(const uint4*)tmp;
    }
  } else {                                       // V 64t source tiles 0..63 -> two 32t [d][t] tiles
    int z2 = z - 8064;
    int b = z2 / 512, r = z2 % 512, kv = r / 64, tile = r % 64;
    if (tile < 63){
      const float* src = pastv + ((size_t)(beam[b] * 8 + kv) * 4032 + tile * 64) * 128;
      #pragma unroll
      for (int it = 0; it < 4; ++it){
        int i = tid + it * 256;
        int t = i >> 4, d0 = (i & 15) * 8;
        const float* s8 = src + t * 128 + d0;
        float4 a = *(const float4*)s8;
        float4 c = *(const float4*)(s8 + 4);
        float vv[8] = {a.x, a.y, a.z, a.w, c.x, c.y, c.z, c.w};
        #pragma unroll
        for (int j = 0; j < 8; ++j) T[t * 129 + d0 + j] = vv[j];
      }
    } else {
      #pragma unroll
      for (int it = 0; it < 4; ++it){
        int i = tid + it * 256;
        int t = i >> 4, d0 = (i & 15) * 8;
        uint4 raw = *(const uint4*)(qkvp + (size_t)(b * 64 + t) * 6144 + 5120 + kv * 128 + d0);
        u16 tmp[8]; *(uint4*)tmp = raw;
        #pragma unroll
        for (int j = 0; j < 8; ++j) T[t * 129 + d0 + j] = bf2f(tmp[j]);
      }
    }
    __syncthreads();
    u16* dstb = vimg + (size_t)((b * 8 + kv) * 128 + tile * 2) * 4096;
    #pragma unroll
    for (int it = 0; it < 4; ++it){
      int ci = tid + it * 256;                   // 1024 total: d(128) x tg(8)
      int d = ci >> 3, tg = ci & 7;              // tg = group of 8 t
      u16* dst = dstb + (tg >> 2) * 4096 + d * 32;
      #pragma unroll
      for (int h = 0; h < 2; ++h){
        int c = (tg & 3) * 2 + h;
        int cs = c ^ (d & 7);
        u16 tmp[4];
        #pragma unroll
        for (int k = 0; k < 4; ++k) tmp[k] = f2bf(T[(tg * 8 + h * 4 + k) * 129 + d]);
        *(uint2*)(dst + cs * 4) = *(const uint2*)tmp;
      }
    }
  }
}

// ---------------- flash attention over one T-chunk of 1024 (swapped-operand, P in registers) ----------------
__global__ __launch_bounds__(256, 2) void attn_kernel(const u16* __restrict__ qrope, const u16* __restrict__ kimg,
                                                      const u16* __restrict__ vimg, float* __restrict__ pctx,
                                                      float* __restrict__ pm, float* __restrict__ pl){
  __shared__ u16 Ks[2][4096];   // [buf][32 t * 128 d]  (kimg swizzle baked in)
  __shared__ u16 Vs[2][4096];   // [buf][128 d * 32 t]  (vimg swizzle baked in)
  int kv = blockIdx.x, b = blockIdx.y, chunk = blockIdx.z;
  int tid = threadIdx.x, lane = tid & 63, g = tid >> 6;
  int l15 = lane & 15, lh = lane >> 4;
  int wub = g * 1024;

  // Q fragments resident (pre-scaled by CSC in rope): Q[q=qm*16+l15][d-chunk ks*32+lh*8]
  const u16* qb = qrope + (size_t)((b * 32 + kv * 4 + g) * 64) * 128;
  uint4 qf[4][4];
  #pragma unroll
  for (int qm = 0; qm < 4; ++qm)
    #pragma unroll
    for (int ks = 0; ks < 4; ++ks)
      qf[qm][ks] = *(const uint4*)(qb + (size_t)(qm * 16 + l15) * 128 + ks * 32 + lh * 8);

  f32x4 cacc[8][4];             // [nd][qm]: ctx^T rows d=nd*16+lh*4+r, cols q=qm*16+l15
  float mrow[4], lrow[4];
  #pragma unroll
  for (int qm = 0; qm < 4; ++qm){ mrow[qm] = -3.0e38f; lrow[qm] = 0.f; }
  #pragma unroll
  for (int nd = 0; nd < 8; ++nd)
    #pragma unroll
    for (int qm = 0; qm < 4; ++qm) cacc[nd][qm] = f32x4{0.f, 0.f, 0.f, 0.f};

  const char* kbase = (const char*)(kimg + (size_t)(b * 8 + kv) * 524288) + (size_t)chunk * 262144;
  const char* vbase = (const char*)(vimg + (size_t)(b * 8 + kv) * 524288) + (size_t)chunk * 262144;

  llds16(kbase + tid * 16,        (char*)Ks + wub);
  llds16(kbase + 4096 + tid * 16, (char*)Ks + 4096 + wub);
  llds16(vbase + tid * 16,        (char*)Vs + wub);
  llds16(vbase + 4096 + tid * 16, (char*)Vs + 4096 + wub);
  __syncthreads();

  for (int it = 0; it < 32; ++it){
    int cur = it & 1;
    if (it < 31){
      const char* kt = kbase + (size_t)(it + 1) * 8192;
      const char* vt = vbase + (size_t)(it + 1) * 8192;
      char* kl = (char*)Ks + (cur ^ 1) * 8192 + wub;
      char* vl = (char*)Vs + (cur ^ 1) * 8192 + wub;
      llds16(kt + tid * 16,        kl);
      llds16(kt + 4096 + tid * 16, kl + 4096);
      llds16(vt + tid * 16,        vl);
      llds16(vt + 4096 + tid * 16, vl + 4096);
    }

    // S^T = K * Q^T : sacc[tt][qm] rows t=tt*16+lh*4+r, cols q=qm*16+l15
    const u16* Kc = (const u16*)((const char*)Ks + cur * 8192);
    const u16* Vc = (const u16*)((const char*)Vs + cur * 8192);
    f32x4 sacc[2][4];
    #pragma unroll
    for (int tt = 0; tt < 2; ++tt)
      #pragma unroll
      for (int qm = 0; qm < 4; ++qm) sacc[tt][qm] = f32x4{0.f, 0.f, 0.f, 0.f};
    #pragma unroll
    for (int ks = 0; ks < 4; ++ks){
      int dc = ks * 4 + lh;
      int dcs = (dc & 8) | ((dc ^ l15) & 7);
      uint4 kf0 = *(const uint4*)(Kc + (size_t)l15 * 128 + dcs * 8);
      uint4 kf1 = *(const uint4*)(Kc + (size_t)(16 + l15) * 128 + dcs * 8);
      #pragma unroll
      for (int qm = 0; qm < 4; ++qm){
        sacc[0][qm] = __builtin_amdgcn_mfma_f32_16x16x32_bf16(as_bf(kf0), as_bf(qf[qm][ks]), sacc[0][qm], 0, 0, 0);
        sacc[1][qm] = __builtin_amdgcn_mfma_f32_16x16x32_bf16(as_bf(kf1), as_bf(qf[qm][ks]), sacc[1][qm], 0, 0, 0);
      }
    }

    // causal mask: only last two tiles of chunk 3 (new tokens)
    if (chunk == 3 && it >= 30){
      int toff = (it - 30) * 32;
      #pragma unroll
      for (int tt = 0; tt < 2; ++tt)
        #pragma unroll
        for (int qm = 0; qm < 4; ++qm)
          #pragma unroll
          for (int r = 0; r < 4; ++r){
            int t = toff + tt * 16 + lh * 4 + r;
            int q = qm * 16 + l15;
            if (t > q) sacc[tt][qm][r] = -3.0e38f;
          }
    }

    // online softmax, lane-local per q (replicated over lh groups)
    #pragma unroll
    for (int qm = 0; qm < 4; ++qm){
      float rm = sacc[0][qm][0];
      #pragma unroll
      for (int tt = 0; tt < 2; ++tt)
        #pragma unroll
        for (int r = 0; r < 4; ++r) rm = fmaxf(rm, sacc[tt][qm][r]);
      rm = fmaxf(rm, __shfl_xor(rm, 16));
      rm = fmaxf(rm, __shfl_xor(rm, 32));
      if (__any(rm > mrow[qm] + 8.0f)){     // defer-max: rescale only when max grows materially
        float mn = fmaxf(mrow[qm], rm);
        float esc = exp2f(mrow[qm] - mn);
        mrow[qm] = mn;
        lrow[qm] *= esc;
        #pragma unroll
        for (int nd = 0; nd < 8; ++nd) cacc[nd][qm] *= esc;
      }
      float s = 0.f;
      #pragma unroll
      for (int tt = 0; tt < 2; ++tt)
        #pragma unroll
        for (int r = 0; r < 4; ++r){
          float p = exp2f(sacc[tt][qm][r] - mrow[qm]);
          sacc[tt][qm][r] = p;
          s += p;
        }
      s += __shfl_xor(s, 16);
      s += __shfl_xor(s, 32);
      lrow[qm] += s;
    }

    // ctx^T += V^T * P^T via 16x16x16 MFMA (P stays in registers)
    #pragma unroll
    for (int tt = 0; tt < 2; ++tt){
      s16x4 pa[4];
      #pragma unroll
      for (int qm = 0; qm < 4; ++qm){
        uint2 u;
        u.x = cvtpk(sacc[tt][qm][0], sacc[tt][qm][1]);
        u.y = cvtpk(sacc[tt][qm][2], sacc[tt][qm][3]);
        pa[qm] = __builtin_bit_cast(s16x4, u);
      }
      #pragma unroll
      for (int nd = 0; nd < 8; ++nd){
        int c = tt * 4 + lh;
        uint2 vr = *(const uint2*)(Vc + (size_t)(nd * 16 + l15) * 32 + ((c ^ (l15 & 7)) * 4));
        s16x4 vfr = __builtin_bit_cast(s16x4, vr);
        #pragma unroll
        for (int qm = 0; qm < 4; ++qm)
          cacc[nd][qm] = mfma16(vfr, pa[qm], cacc[nd][qm]);
      }
    }
    __syncthreads();
  }

  // unnormalized partials (contiguous stores) + (m,l)
  float* pc = pctx + (size_t)(((chunk * 16 + b) * 8 + kv) * 4 + g) * 8192;
  #pragma unroll
  for (int qm = 0; qm < 4; ++qm){
    int q = qm * 16 + l15;
    #pragma unroll
    for (int nd = 0; nd < 8; ++nd)
      *(f32x4*)(pc + (size_t)q * 128 + nd * 16 + lh * 4) = cacc[nd][qm];
  }
  if (lh == 0){
    size_t mb = (size_t)((chunk * 16 + b) * 8 + kv) * 256 + g * 64;
    #pragma unroll
    for (int qm = 0; qm < 4; ++qm){
      pm[mb + qm * 16 + l15] = mrow[qm];
      pl[mb + qm * 16 + l15] = lrow[qm];
    }
  }
}

// ---------------- combine the 4 chunk partials ----------------
__global__ __launch_bounds__(256) void combine_kernel(const float* __restrict__ pctx, const float* __restrict__ pm,
                                                      const float* __restrict__ pl, u16* __restrict__ ctxb){
  int z = blockIdx.x;
  int g = z & 3, kv = (z >> 2) & 7, b = z >> 5;
  int tid = threadIdx.x;
  int s = tid >> 2, dq = (tid & 3) * 32;
  float mv[4], lv[4];
  #pragma unroll
  for (int c = 0; c < 4; ++c){
    size_t mi = (size_t)((c * 16 + b) * 8 + kv) * 256 + g * 64 + s;
    mv[c] = pm[mi]; lv[c] = pl[mi];
  }
  float M = fmaxf(fmaxf(mv[0], mv[1]), fmaxf(mv[2], mv[3]));
  float wc[4], wsum = 0.f;
  #pragma unroll
  for (int c = 0; c < 4; ++c){ wc[c] = exp2f(mv[c] - M); wsum += wc[c] * lv[c]; }
  float inv = 1.0f / wsum;
  u16* dst = ctxb + (size_t)(b * 64 + s) * 4096 + (kv * 4 + g) * 128 + dq;
  #pragma unroll
  for (int j4 = 0; j4 < 8; ++j4){
    float4 a = {0.f, 0.f, 0.f, 0.f};
    #pragma unroll
    for (int c = 0; c < 4; ++c){
      const float* p = pctx + (size_t)(((c * 16 + b) * 8 + kv) * 4 + g) * 8192 + s * 128 + dq + j4 * 4;
      float4 v = *(const float4*)p;
      a.x += wc[c] * v.x; a.y += wc[c] * v.y; a.z += wc[c] * v.z; a.w += wc[c] * v.w;
    }
    u16 t4[4] = {f2bf(a.x * inv), f2bf(a.y * inv), f2bf(a.z * inv), f2bf(a.w * inv)};
    *(uint2*)(dst + j4 * 4) = *(const uint2*)t4;
  }
}

extern "C" void kernel_launch(void* const* d_in, const int* in_sizes, int n_in,
                              void* d_out, int out_size, void* d_ws, size_t ws_size,
                              hipStream_t stream){
  const float* hidden = (const float*)d_in[0];
  const float* pastk  = (const float*)d_in[1];
  const float* pastv  = (const float*)d_in[2];
  const float* qw     = (const float*)d_in[3];
  const float* kw     = (const float*)d_in[4];
  const float* vw     = (const float*)d_in[5];
  const float* ow     = (const float*)d_in[6];
  const int*   beam   = (const int*)d_in[7];

  char* ws = (char*)d_ws;
  size_t off = 0;
  auto alloc = [&](size_t sz){ char* p = ws + off; off += sz; return p; };
  u16*   wtall = (u16*)alloc(50331648);     // [6144][4096] bf16: q,k,v weights transposed
  u16*   wto   = (u16*)alloc(33554432);     // [4096][4096] bf16: out_wei transposed
  u16*   hidb  = (u16*)alloc(8388608);      // hidden bf16 [1024][4096]
  u16*   qkvp  = (u16*)alloc(12582912);     // QKV proj [1024][6144]
  u16*   qrope = (u16*)alloc(8388608);      // [16][32][64][128]
  u16*   kimg  = (u16*)alloc(134217728);    // [16][8][64 tiles][64x128 swz]
  u16*   vimg  = (u16*)alloc(134217728);    // [16][8][128 tiles][128x32 swz, transposed]
  float* pctx  = (float*)alloc(67108864);   // [4][16][8][4][64][128]
  float* pm    = (float*)alloc(524288);
  float* pl    = (float*)alloc(524288);
  u16*   ctxb  = (u16*)alloc(8388608);      // [1024][4096]
  if (off > ws_size) return;                // workspace too small -> fail loudly

  cvt_hid_kernel<<<2048, 256, 0, stream>>>(hidden, hidb);
  wtrans_kernel<<<10240, 256, 0, stream>>>(qw, kw, vw, ow, wtall, wto);
  gemm_kernel<0><<<384, 256, 0, stream>>>(hidb, wtall, (void*)qkvp, 6144, 48);
  rope_kernel<<<640, 256, 0, stream>>>(qkvp, qrope, kimg);
  imgbuild_kernel<<<16256, 256, 0, stream>>>(pastk, pastv, qkvp, beam, kimg, vimg);
  attn_kernel<<<dim3(8, 16, 4), 256, 0, stream>>>(qrope, kimg, vimg, pctx, pm, pl);
  combine_kernel<<<512, 256, 0, stream>>>(pctx, pm, pl, ctxb);
  gemm_kernel<1><<<256, 256, 0, stream>>>(ctxb, wto, d_out, 4096, 32);
}

// Round 3
// 481.122 us; speedup vs baseline: 1.5846x; 1.3016x over previous
//
#include <hip/hip_runtime.h>
#include <stdint.h>

#define DEVFN __device__ __forceinline__

typedef unsigned short u16;
typedef unsigned int u32;

using f32x4 = __attribute__((ext_vector_type(4))) float;
using bfv8  = __attribute__((ext_vector_type(8))) short;   // 8 bf16 = 4 VGPR
using s16x4 = __attribute__((ext_vector_type(4))) short;   // 4 bf16 = 2 VGPR

#define CSC 0.12751745f   // (1/sqrt(128)) * log2(e)  -- folded into Q

DEVFN u16 f2bf(float f){
  u32 u = __float_as_uint(f);
  u32 r = u + 0x7FFFu + ((u >> 16) & 1u);
  return (u16)(r >> 16);
}
DEVFN float bf2f(u16 h){ return __uint_as_float(((u32)h) << 16); }

DEVFN void llds16(const void* g, void* l){
  __builtin_amdgcn_global_load_lds((const __attribute__((address_space(1))) void*)g,
                                   (__attribute__((address_space(3))) void*)l, 16, 0, 0);
}

DEVFN bfv8 as_bf(uint4 v){ return __builtin_bit_cast(bfv8, v); }

#if __has_builtin(__builtin_amdgcn_mfma_f32_16x16x16bf16_1k)
DEVFN f32x4 mfma16(s16x4 a, s16x4 b, f32x4 c){
  return __builtin_amdgcn_mfma_f32_16x16x16bf16_1k(a, b, c, 0, 0, 0);
}
#else
DEVFN f32x4 mfma16(s16x4 a, s16x4 b, f32x4 c){
  asm("v_mfma_f32_16x16x16_bf16 %0, %1, %2, %0" : "+v"(c) : "v"(a), "v"(b));
  return c;
}
#endif

DEVFN u32 cvtpk(float lo, float hi){
  u32 w;
  asm("v_cvt_pk_bf16_f32 %0, %1, %2" : "=v"(w) : "v"(lo), "v"(hi));
  return w;
}

// ---------------- cast hidden fp32 -> bf16 ----------------
__global__ __launch_bounds__(256) void cvt_hid_kernel(const float* __restrict__ src, u16* __restrict__ dst){
  int i = blockIdx.x * 256 + threadIdx.x;           // 8 elems per thread
  const float* s = src + (size_t)i * 8;
  float4 a = *(const float4*)s;
  float4 b = *(const float4*)(s + 4);
  u16 t[8] = {f2bf(a.x), f2bf(a.y), f2bf(a.z), f2bf(a.w),
              f2bf(b.x), f2bf(b.y), f2bf(b.z), f2bf(b.w)};
  *(uint4*)(dst + (size_t)i * 8) = *(const uint4*)t;
}

// ---------------- weights: fp32 [K][N] -> bf16 B^T [N][K] (K=4096) ----------------
__global__ __launch_bounds__(256) void wtrans_kernel(const float* __restrict__ qw, const float* __restrict__ kw,
                                                     const float* __restrict__ vw, const float* __restrict__ ow,
                                                     u16* __restrict__ wtall, u16* __restrict__ wto){
  __shared__ float tile[64 * 65];
  int z = blockIdx.x, tid = threadIdx.x;
  const float* W; u16* WT; int Ndim; int rz;
  if (z < 4096)      { W = qw; WT = wtall;                         Ndim = 4096; rz = z; }
  else if (z < 5120) { W = kw; WT = wtall + (size_t)4096 * 4096;   Ndim = 1024; rz = z - 4096; }
  else if (z < 6144) { W = vw; WT = wtall + (size_t)5120 * 4096;   Ndim = 1024; rz = z - 5120; }
  else               { W = ow; WT = wto;                           Ndim = 4096; rz = z - 6144; }
  int ntn = Ndim >> 6;
  int tk = rz / ntn, tn = rz % ntn;
  const float* src = W + (size_t)(tk * 64) * Ndim + tn * 64;
  #pragma unroll
  for (int it = 0; it < 4; ++it){
    int fi = tid + it * 256;          // float4 index (1024 total)
    int r = fi >> 4, c4 = (fi & 15) * 4;
    float4 v = *(const float4*)(src + (size_t)r * Ndim + c4);
    tile[r * 65 + c4 + 0] = v.x; tile[r * 65 + c4 + 1] = v.y;
    tile[r * 65 + c4 + 2] = v.z; tile[r * 65 + c4 + 3] = v.w;
  }
  __syncthreads();
  u16* dst = WT + (size_t)(tn * 64) * 4096 + tk * 64;
  #pragma unroll
  for (int it = 0; it < 2; ++it){
    int ci = tid + it * 256;          // chunk of 8 (512 total)
    int n = ci >> 3, k8 = (ci & 7) * 8;
    u16 tmp[8];
    #pragma unroll
    for (int j = 0; j < 8; ++j) tmp[j] = f2bf(tile[(k8 + j) * 65 + n]);
    *(uint4*)(dst + (size_t)n * 4096 + k8) = *(const uint4*)tmp;
  }
}

// ---------------- m97-style bf16 GEMM: C[M,N] = A[M,4096] * (BT[N,4096])^T ----------------
template<int OUTF32>
__global__ __launch_bounds__(256) void gemm_kernel(const u16* __restrict__ A, const u16* __restrict__ BT,
                                                   void* __restrict__ Cv, int N, int ntn){
  constexpr int K = 4096;
  __shared__ u16 As[2][128 * 32];
  __shared__ u16 Bs[2][128 * 32];
  int bid = blockIdx.x;
  int bm = bid / ntn, bn = bid % ntn;
  int tid = threadIdx.x, lane = tid & 63, w = tid >> 6;
  int wr = w >> 1, wc = w & 1;
  int l15 = lane & 15, lh = lane >> 4;
  const u16* Ab = A  + (size_t)(bm * 128) * K;
  const u16* Bb = BT + (size_t)(bn * 128) * K;
  f32x4 acc[4][4];
  #pragma unroll
  for (int m = 0; m < 4; ++m)
    #pragma unroll
    for (int n = 0; n < 4; ++n) acc[m][n] = f32x4{0.f, 0.f, 0.f, 0.f};

  auto stage = [&](int buf, int k0){
    #pragma unroll
    for (int p = 0; p < 2; ++p){
      int cid = tid + p * 256;
      int row = cid >> 2, k8 = (cid & 3) * 8;
      llds16(Ab + (size_t)row * K + k0 + k8, (char*)(&As[buf][0]) + p * 4096 + w * 1024);
      llds16(Bb + (size_t)row * K + k0 + k8, (char*)(&Bs[buf][0]) + p * 4096 + w * 1024);
    }
  };
  stage(0, 0);
  __syncthreads();
  for (int kt = 0; kt < K / 32; ++kt){
    int cur = kt & 1;
    if (kt + 1 < K / 32) stage(cur ^ 1, (kt + 1) * 32);
    uint4 af[4], bfr[4];
    #pragma unroll
    for (int i = 0; i < 4; ++i){
      af[i]  = *(const uint4*)(&As[cur][(wr * 64 + i * 16 + l15) * 32 + lh * 8]);
      bfr[i] = *(const uint4*)(&Bs[cur][(wc * 64 + i * 16 + l15) * 32 + lh * 8]);
    }
    #pragma unroll
    for (int m = 0; m < 4; ++m)
      #pragma unroll
      for (int n = 0; n < 4; ++n)
        acc[m][n] = __builtin_amdgcn_mfma_f32_16x16x32_bf16(as_bf(af[m]), as_bf(bfr[n]), acc[m][n], 0, 0, 0);
    __syncthreads();
  }
  int row0 = bm * 128 + wr * 64, col0 = bn * 128 + wc * 64;
  if (OUTF32){
    float* C = (float*)Cv;
    #pragma unroll
    for (int m = 0; m < 4; ++m)
      #pragma unroll
      for (int n = 0; n < 4; ++n)
        #pragma unroll
        for (int r = 0; r < 4; ++r)
          C[(size_t)(row0 + m * 16 + lh * 4 + r) * N + col0 + n * 16 + l15] = acc[m][n][r];
  } else {
    u16* C = (u16*)Cv;
    #pragma unroll
    for (int m = 0; m < 4; ++m)
      #pragma unroll
      for (int n = 0; n < 4; ++n)
        #pragma unroll
        for (int r = 0; r < 4; ++r)
          C[(size_t)(row0 + m * 16 + lh * 4 + r) * N + col0 + n * 16 + l15] = f2bf(acc[m][n][r]);
  }
}

// ---------------- RoPE: Q (scaled, swizzled) -> qrope ; K -> knew fp32 ; V copy -> vnew fp32 ----------------
__global__ __launch_bounds__(256) void rope_kernel(const u16* __restrict__ qkvp, u16* __restrict__ qrope,
                                                   float* __restrict__ knew, float* __restrict__ vnew){
  int z = blockIdx.x, tid = threadIdx.x;
  if (z < 512){
    int b = z >> 5, h = z & 31;
    u16* dst = qrope + (size_t)((b * 32 + h) * 64) * 128;
    for (int it = 0; it < 16; ++it){
      int i = tid + it * 256;
      int s = i >> 6, j = i & 63;
      const u16* src = qkvp + (size_t)(b * 64 + s) * 6144 + h * 128;
      float q0 = bf2f(src[j]), q1 = bf2f(src[j + 64]);
      float inv = expf(-(float)j * 0.14391157f);      // 1/10000^(j/64)
      float ang = (4032.0f + (float)s) * inv;
      float sn = sinf(ang), cs = cosf(ang);
      // swizzled store: elem (q=s, d) at q*128 + ((dc&8)|((dc^q)&7))*8 + (d&7)
      int dcs = ((j >> 3) ^ s) & 7;
      dst[s * 128 + dcs * 8 + (j & 7)]      = f2bf((q0 * cs - q1 * sn) * CSC);
      dst[s * 128 + 64 + dcs * 8 + (j & 7)] = f2bf((q1 * cs + q0 * sn) * CSC);
    }
  } else {
    int z2 = z - 512, b = z2 >> 3, kvh = z2 & 7;
    for (int it = 0; it < 16; ++it){
      int i = tid + it * 256;
      int s = i >> 6, j = i & 63;
      const u16* src = qkvp + (size_t)(b * 64 + s) * 6144 + 4096 + kvh * 128;
      float q0 = bf2f(src[j]), q1 = bf2f(src[j + 64]);
      float inv = expf(-(float)j * 0.14391157f);
      float ang = (4032.0f + (float)s) * inv;
      float sn = sinf(ang), cs = cosf(ang);
      float* kd = knew + ((size_t)(b * 8 + kvh) * 64 + s) * 128;
      kd[j]      = q0 * cs - q1 * sn;
      kd[j + 64] = q1 * cs + q0 * sn;
      const u16* vs = qkvp + (size_t)(b * 64 + s) * 6144 + 5120 + kvh * 128;
      float* vd = vnew + ((size_t)(b * 8 + kvh) * 64 + s) * 128;
      vd[j]      = bf2f(vs[j]);
      vd[j + 64] = bf2f(vs[j + 64]);
    }
  }
}

// ---------------- flash attention, fused beam-gather + fp32->bf16, producer-consumer waves ----------------
// block: 512 thr = 4 consumer waves (g=0..3, one head each) + 4 producer waves (stage 8t x 128d each)
__global__ __launch_bounds__(512, 2) void attn_kernel(const u16* __restrict__ qrope, const float* __restrict__ pastk,
                                                      const float* __restrict__ pastv, const float* __restrict__ knew,
                                                      const float* __restrict__ vnew, const int* __restrict__ beam,
                                                      float* __restrict__ pctx, float* __restrict__ pm,
                                                      float* __restrict__ pl){
  __shared__ u16 Qs[4][8192];   // per consumer wave: [64 q][128 d], chunk-swizzled (pre-swizzled in qrope)
  __shared__ u16 Ks[2][4096];   // [buf][32 t][128 d], chunk swz (dc&8)|((dc^t)&7)
  __shared__ u16 Vs[2][4096];   // [buf][128 d][32 t], t-chunk(8) swz c ^ (((d>>3)^d)&3)
  int kv = blockIdx.x, b = blockIdx.y, chunk = blockIdx.z;
  int tid = threadIdx.x, lane = tid & 63, w = tid >> 6;
  int l15 = lane & 15, lh = lane >> 4;
  constexpr int NT = 32;

  if (w >= 4){
    // ================= producer =================
    int p = w - 4;
    int dblk = l15;               // 8-d block
    int tq = p * 8 + lh * 2;      // tile-local t (even), stages rows tq, tq+1
    int bmb = beam[b];
    const float* kpast = pastk + (size_t)(bmb * 8 + kv) * 4032 * 128;
    const float* vpast = pastv + (size_t)(bmb * 8 + kv) * 4032 * 128;
    const float* knb = knew + (size_t)(b * 8 + kv) * 64 * 128;
    const float* vnb = vnew + (size_t)(b * 8 + kv) * 64 * 128;

    auto stageTile = [&](int tix, int buf){
      int tg0 = chunk * 1024 + tix * 32;
      const float *ksrc, *vsrc;
      if (tg0 >= 4032){ ksrc = knb + (size_t)(tg0 - 4032) * 128; vsrc = vnb + (size_t)(tg0 - 4032) * 128; }
      else            { ksrc = kpast + (size_t)tg0 * 128;         vsrc = vpast + (size_t)tg0 * 128; }
      int t0 = tq, t1 = tq + 1;
      const float* k0p = ksrc + (size_t)t0 * 128 + dblk * 8;
      const float* k1p = ksrc + (size_t)t1 * 128 + dblk * 8;
      const float* v0p = vsrc + (size_t)t0 * 128 + dblk * 8;
      const float* v1p = vsrc + (size_t)t1 * 128 + dblk * 8;
      float4 k00 = *(const float4*)k0p; float4 k01 = *(const float4*)(k0p + 4);
      float4 k10 = *(const float4*)k1p; float4 k11 = *(const float4*)(k1p + 4);
      float4 v00 = *(const float4*)v0p; float4 v01 = *(const float4*)(v0p + 4);
      float4 v10 = *(const float4*)v1p; float4 v11 = *(const float4*)(v1p + 4);
      // K rows (b128 each)
      {
        uint4 pk;
        pk.x = cvtpk(k00.x, k00.y); pk.y = cvtpk(k00.z, k00.w);
        pk.z = cvtpk(k01.x, k01.y); pk.w = cvtpk(k01.z, k01.w);
        int dcs0 = (dblk & 8) | ((dblk ^ t0) & 7);
        *(uint4*)(&Ks[buf][t0 * 128 + dcs0 * 8]) = pk;
        uint4 pk1;
        pk1.x = cvtpk(k10.x, k10.y); pk1.y = cvtpk(k10.z, k10.w);
        pk1.z = cvtpk(k11.x, k11.y); pk1.w = cvtpk(k11.z, k11.w);
        int dcs1 = (dblk & 8) | ((dblk ^ t1) & 7);
        *(uint4*)(&Ks[buf][t1 * 128 + dcs1 * 8]) = pk1;
      }
      // V transposed columns (b32 each: bf16(t0,d), bf16(t1,d))
      float va[8] = {v00.x, v00.y, v00.z, v00.w, v01.x, v01.y, v01.z, v01.w};
      float vb[8] = {v10.x, v10.y, v10.z, v10.w, v11.x, v11.y, v11.z, v11.w};
      #pragma unroll
      for (int dd = 0; dd < 8; ++dd){
        int d = dblk * 8 + dd;
        int cc = (p ^ ((dblk ^ dd) & 3)) & 3;      // c=p (t>>3), swz = ((d>>3)^d)&3
        u32 pv = cvtpk(va[dd], vb[dd]);
        *(u32*)(&Vs[buf][d * 32 + cc * 8 + lh * 2]) = pv;
      }
    };

    stageTile(0, 0);
    asm volatile("s_waitcnt lgkmcnt(0)" ::: "memory");
    __builtin_amdgcn_sched_barrier(0);
    __builtin_amdgcn_s_barrier();
    __builtin_amdgcn_sched_barrier(0);
    for (int it = 0; it < NT; ++it){
      if (it < NT - 1){
        stageTile(it + 1, (it + 1) & 1);
        asm volatile("s_waitcnt lgkmcnt(0)" ::: "memory");
      }
      __builtin_amdgcn_sched_barrier(0);
      __builtin_amdgcn_s_barrier();
      __builtin_amdgcn_sched_barrier(0);
    }
    return;
  }

  // ================= consumer =================
  // stage own Q (pre-swizzled in qrope -> linear copy keeps swizzle)
  const u16* qb = qrope + (size_t)((b * 32 + kv * 4 + w) * 64) * 128;
  #pragma unroll
  for (int c = 0; c < 16; ++c)
    llds16((const char*)qb + c * 1024 + lane * 16, (char*)(&Qs[w][0]) + c * 1024);
  asm volatile("s_waitcnt vmcnt(0)" ::: "memory");

  f32x4 cacc[8][4];             // [nd][qm]: ctx^T rows d=nd*16+lh*4+r, cols q=qm*16+l15
  float mrow[4], lrow[4];
  #pragma unroll
  for (int qm = 0; qm < 4; ++qm){ mrow[qm] = -3.0e38f; lrow[qm] = 0.f; }
  #pragma unroll
  for (int nd = 0; nd < 8; ++nd)
    #pragma unroll
    for (int qm = 0; qm < 4; ++qm) cacc[nd][qm] = f32x4{0.f, 0.f, 0.f, 0.f};

  __builtin_amdgcn_sched_barrier(0);
  __builtin_amdgcn_s_barrier();
  __builtin_amdgcn_sched_barrier(0);

  for (int it = 0; it < NT; ++it){
    const u16* Kc = &Ks[it & 1][0];
    const u16* Vc = &Vs[it & 1][0];

    // S^T = K * Q^T : sacc[tt][qm] rows t=tt*16+lh*4+r, cols q=qm*16+l15
    f32x4 sacc[2][4];
    #pragma unroll
    for (int tt = 0; tt < 2; ++tt)
      #pragma unroll
      for (int qm = 0; qm < 4; ++qm) sacc[tt][qm] = f32x4{0.f, 0.f, 0.f, 0.f};
    #pragma unroll
    for (int ks = 0; ks < 4; ++ks){
      int dc = ks * 4 + lh;
      int dcs = (dc & 8) | ((dc ^ l15) & 7);
      uint4 kf0 = *(const uint4*)(Kc + l15 * 128 + dcs * 8);
      uint4 kf1 = *(const uint4*)(Kc + (16 + l15) * 128 + dcs * 8);
      #pragma unroll
      for (int qm = 0; qm < 4; ++qm){
        uint4 qf = *(const uint4*)(&Qs[w][(qm * 16 + l15) * 128 + dcs * 8]);
        sacc[0][qm] = __builtin_amdgcn_mfma_f32_16x16x32_bf16(as_bf(kf0), as_bf(qf), sacc[0][qm], 0, 0, 0);
        sacc[1][qm] = __builtin_amdgcn_mfma_f32_16x16x32_bf16(as_bf(kf1), as_bf(qf), sacc[1][qm], 0, 0, 0);
      }
    }

    // causal mask: only last two tiles of chunk 3 (new tokens)
    if (chunk == 3 && it >= 30){
      int toff = (it - 30) * 32;
      #pragma unroll
      for (int tt = 0; tt < 2; ++tt)
        #pragma unroll
        for (int qm = 0; qm < 4; ++qm)
          #pragma unroll
          for (int r = 0; r < 4; ++r){
            int t = toff + tt * 16 + lh * 4 + r;
            int q = qm * 16 + l15;
            if (t > q) sacc[tt][qm][r] = -3.0e38f;
          }
    }

    // online softmax, lane-local per q (replicated over lh groups)
    #pragma unroll
    for (int qm = 0; qm < 4; ++qm){
      float rm = sacc[0][qm][0];
      #pragma unroll
      for (int tt = 0; tt < 2; ++tt)
        #pragma unroll
        for (int r = 0; r < 4; ++r) rm = fmaxf(rm, sacc[tt][qm][r]);
      rm = fmaxf(rm, __shfl_xor(rm, 16));
      rm = fmaxf(rm, __shfl_xor(rm, 32));
      if (__any(rm > mrow[qm] + 8.0f)){     // defer-max
        float mn = fmaxf(mrow[qm], rm);
        float esc = exp2f(mrow[qm] - mn);
        mrow[qm] = mn;
        lrow[qm] *= esc;
        #pragma unroll
        for (int nd = 0; nd < 8; ++nd) cacc[nd][qm] *= esc;
      }
      float s = 0.f;
      #pragma unroll
      for (int tt = 0; tt < 2; ++tt)
        #pragma unroll
        for (int r = 0; r < 4; ++r){
          float pp = exp2f(sacc[tt][qm][r] - mrow[qm]);
          sacc[tt][qm][r] = pp;
          s += pp;
        }
      s += __shfl_xor(s, 16);
      s += __shfl_xor(s, 32);
      lrow[qm] += s;
    }

    // ctx^T += V^T * P^T via 16x16x16 MFMA (P in registers)
    #pragma unroll
    for (int tt = 0; tt < 2; ++tt){
      s16x4 pa[4];
      #pragma unroll
      for (int qm = 0; qm < 4; ++qm){
        uint2 u;
        u.x = cvtpk(sacc[tt][qm][0], sacc[tt][qm][1]);
        u.y = cvtpk(sacc[tt][qm][2], sacc[tt][qm][3]);
        pa[qm] = __builtin_bit_cast(s16x4, u);
      }
      #pragma unroll
      for (int nd = 0; nd < 8; ++nd){
        int swzv = ((nd * 2) ^ (l15 >> 3) ^ l15) & 3;          // ((d>>3)^d)&3
        int cc = ((tt * 2 + (lh >> 1)) ^ swzv) & 3;
        uint2 vr = *(const uint2*)(Vc + (nd * 16 + l15) * 32 + cc * 8 + (lh & 1) * 4);
        s16x4 vfr = __builtin_bit_cast(s16x4, vr);
        #pragma unroll
        for (int qm = 0; qm < 4; ++qm)
          cacc[nd][qm] = mfma16(vfr, pa[qm], cacc[nd][qm]);
      }
    }
    __builtin_amdgcn_sched_barrier(0);
    __builtin_amdgcn_s_barrier();
    __builtin_amdgcn_sched_barrier(0);
  }

  // unnormalized partials (contiguous stores) + (m,l)
  float* pc = pctx + (size_t)(((chunk * 16 + b) * 8 + kv) * 4 + w) * 8192;
  #pragma unroll
  for (int qm = 0; qm < 4; ++qm){
    int q = qm * 16 + l15;
    #pragma unroll
    for (int nd = 0; nd < 8; ++nd)
      *(f32x4*)(pc + (size_t)q * 128 + nd * 16 + lh * 4) = cacc[nd][qm];
  }
  if (lh == 0){
    size_t mb = (size_t)((chunk * 16 + b) * 8 + kv) * 256 + w * 64;
    #pragma unroll
    for (int qm = 0; qm < 4; ++qm){
      pm[mb + qm * 16 + l15] = mrow[qm];
      pl[mb + qm * 16 + l15] = lrow[qm];
    }
  }
}

// ---------------- combine the 4 chunk partials ----------------
__global__ __launch_bounds__(256) void combine_kernel(const float* __restrict__ pctx, const float* __restrict__ pm,
                                                      const float* __restrict__ pl, u16* __restrict__ ctxb){
  int z = blockIdx.x;
  int g = z & 3, kv = (z >> 2) & 7, b = z >> 5;
  int tid = threadIdx.x;
  int s = tid >> 2, dq = (tid & 3) * 32;
  float mv[4], lv[4];
  #pragma unroll
  for (int c = 0; c < 4; ++c){
    size_t mi = (size_t)((c * 16 + b) * 8 + kv) * 256 + g * 64 + s;
    mv[c] = pm[mi]; lv[c] = pl[mi];
  }
  float M = fmaxf(fmaxf(mv[0], mv[1]), fmaxf(mv[2], mv[3]));
  float wc[4], wsum = 0.f;
  #pragma unroll
  for (int c = 0; c < 4; ++c){ wc[c] = exp2f(mv[c] - M); wsum += wc[c] * lv[c]; }
  float inv = 1.0f / wsum;
  u16* dst = ctxb + (size_t)(b * 64 + s) * 4096 + (kv * 4 + g) * 128 + dq;
  #pragma unroll
  for (int j4 = 0; j4 < 8; ++j4){
    float4 a = {0.f, 0.f, 0.f, 0.f};
    #pragma unroll
    for (int c = 0; c < 4; ++c){
      const float* p = pctx + (size_t)(((c * 16 + b) * 8 + kv) * 4 + g) * 8192 + s * 128 + dq + j4 * 4;
      float4 v = *(const float4*)p;
      a.x += wc[c] * v.x; a.y += wc[c] * v.y; a.z += wc[c] * v.z; a.w += wc[c] * v.w;
    }
    u16 t4[4] = {f2bf(a.x * inv), f2bf(a.y * inv), f2bf(a.z * inv), f2bf(a.w * inv)};
    *(uint2*)(dst + j4 * 4) = *(const uint2*)t4;
  }
}

extern "C" void kernel_launch(void* const* d_in, const int* in_sizes, int n_in,
                              void* d_out, int out_size, void* d_ws, size_t ws_size,
                              hipStream_t stream){
  const float* hidden = (const float*)d_in[0];
  const float* pastk  = (const float*)d_in[1];
  const float* pastv  = (const float*)d_in[2];
  const float* qw     = (const float*)d_in[3];
  const float* kw     = (const float*)d_in[4];
  const float* vw     = (const float*)d_in[5];
  const float* ow     = (const float*)d_in[6];
  const int*   beam   = (const int*)d_in[7];

  char* ws = (char*)d_ws;
  size_t off = 0;
  auto alloc = [&](size_t sz){ char* p = ws + off; off += sz; return p; };
  u16*   wtall = (u16*)alloc(50331648);     // [6144][4096] bf16: q,k,v weights transposed
  u16*   wto   = (u16*)alloc(33554432);     // [4096][4096] bf16: out_wei transposed
  u16*   hidb  = (u16*)alloc(8388608);      // hidden bf16 [1024][4096]
  u16*   qkvp  = (u16*)alloc(12582912);     // QKV proj [1024][6144]
  u16*   qrope = (u16*)alloc(8388608);      // [16][32][64][128] swizzled
  float* knew  = (float*)alloc(4194304);    // [16][8][64][128] fp32 roped new K
  float* vnew  = (float*)alloc(4194304);    // [16][8][64][128] fp32 new V
  float* pctx  = (float*)alloc(67108864);   // [4][16][8][4][64][128]
  float* pm    = (float*)alloc(524288);
  float* pl    = (float*)alloc(524288);
  u16*   ctxb  = (u16*)alloc(8388608);      // [1024][4096]
  if (off > ws_size) return;                // workspace too small -> fail loudly

  cvt_hid_kernel<<<2048, 256, 0, stream>>>(hidden, hidb);
  wtrans_kernel<<<10240, 256, 0, stream>>>(qw, kw, vw, ow, wtall, wto);
  gemm_kernel<0><<<384, 256, 0, stream>>>(hidb, wtall, (void*)qkvp, 6144, 48);
  rope_kernel<<<640, 256, 0, stream>>>(qkvp, qrope, knew, vnew);
  attn_kernel<<<dim3(8, 16, 4), 512, 0, stream>>>(qrope, pastk, pastv, knew, vnew, beam, pctx, pm, pl);
  combine_kernel<<<512, 256, 0, stream>>>(pctx, pm, pl, ctxb);
  gemm_kernel<1><<<256, 256, 0, stream>>>(ctxb, wto, d_out, 4096, 32);
}

// Round 4
// 460.368 us; speedup vs baseline: 1.6560x; 1.0451x over previous
//
#include <hip/hip_runtime.h>
#include <stdint.h>

#define DEVFN __device__ __forceinline__

typedef unsigned short u16;
typedef unsigned int u32;

using f32x4 = __attribute__((ext_vector_type(4))) float;
using bfv8  = __attribute__((ext_vector_type(8))) short;   // 8 bf16 = 4 VGPR
using s16x4 = __attribute__((ext_vector_type(4))) short;   // 4 bf16 = 2 VGPR

#define CSC 0.12751745f   // (1/sqrt(128)) * log2(e)  -- folded into Q

DEVFN u16 f2bf(float f){
  u32 u = __float_as_uint(f);
  u32 r = u + 0x7FFFu + ((u >> 16) & 1u);
  return (u16)(r >> 16);
}
DEVFN float bf2f(u16 h){ return __uint_as_float(((u32)h) << 16); }

DEVFN void llds16(const void* g, void* l){
  __builtin_amdgcn_global_load_lds((const __attribute__((address_space(1))) void*)g,
                                   (__attribute__((address_space(3))) void*)l, 16, 0, 0);
}

DEVFN bfv8 as_bf(uint4 v){ return __builtin_bit_cast(bfv8, v); }

#if __has_builtin(__builtin_amdgcn_mfma_f32_16x16x16bf16_1k)
DEVFN f32x4 mfma16(s16x4 a, s16x4 b, f32x4 c){
  return __builtin_amdgcn_mfma_f32_16x16x16bf16_1k(a, b, c, 0, 0, 0);
}
#else
DEVFN f32x4 mfma16(s16x4 a, s16x4 b, f32x4 c){
  asm("v_mfma_f32_16x16x16_bf16 %0, %1, %2, %0" : "+v"(c) : "v"(a), "v"(b));
  return c;
}
#endif

DEVFN u32 cvtpk(float lo, float hi){
  u32 w;
  asm("v_cvt_pk_bf16_f32 %0, %1, %2" : "=v"(w) : "v"(lo), "v"(hi));
  return w;
}

// ---------------- cast hidden fp32 -> bf16 ----------------
__global__ __launch_bounds__(256) void cvt_hid_kernel(const float* __restrict__ src, u16* __restrict__ dst){
  int i = blockIdx.x * 256 + threadIdx.x;           // 8 elems per thread
  const float* s = src + (size_t)i * 8;
  float4 a = *(const float4*)s;
  float4 b = *(const float4*)(s + 4);
  u16 t[8] = {f2bf(a.x), f2bf(a.y), f2bf(a.z), f2bf(a.w),
              f2bf(b.x), f2bf(b.y), f2bf(b.z), f2bf(b.w)};
  *(uint4*)(dst + (size_t)i * 8) = *(const uint4*)t;
}

// ---------------- weights: fp32 [K][N] -> bf16 B^T [N][K] (K=4096) ----------------
__global__ __launch_bounds__(256) void wtrans_kernel(const float* __restrict__ qw, const float* __restrict__ kw,
                                                     const float* __restrict__ vw, const float* __restrict__ ow,
                                                     u16* __restrict__ wtall, u16* __restrict__ wto){
  __shared__ float tile[64 * 65];
  int z = blockIdx.x, tid = threadIdx.x;
  const float* W; u16* WT; int Ndim; int rz;
  if (z < 4096)      { W = qw; WT = wtall;                         Ndim = 4096; rz = z; }
  else if (z < 5120) { W = kw; WT = wtall + (size_t)4096 * 4096;   Ndim = 1024; rz = z - 4096; }
  else if (z < 6144) { W = vw; WT = wtall + (size_t)5120 * 4096;   Ndim = 1024; rz = z - 5120; }
  else               { W = ow; WT = wto;                           Ndim = 4096; rz = z - 6144; }
  int ntn = Ndim >> 6;
  int tk = rz / ntn, tn = rz % ntn;
  const float* src = W + (size_t)(tk * 64) * Ndim + tn * 64;
  #pragma unroll
  for (int it = 0; it < 4; ++it){
    int fi = tid + it * 256;          // float4 index (1024 total)
    int r = fi >> 4, c4 = (fi & 15) * 4;
    float4 v = *(const float4*)(src + (size_t)r * Ndim + c4);
    tile[r * 65 + c4 + 0] = v.x; tile[r * 65 + c4 + 1] = v.y;
    tile[r * 65 + c4 + 2] = v.z; tile[r * 65 + c4 + 3] = v.w;
  }
  __syncthreads();
  u16* dst = WT + (size_t)(tn * 64) * 4096 + tk * 64;
  #pragma unroll
  for (int it = 0; it < 2; ++it){
    int ci = tid + it * 256;          // chunk of 8 (512 total)
    int n = ci >> 3, k8 = (ci & 7) * 8;
    u16 tmp[8];
    #pragma unroll
    for (int j = 0; j < 8; ++j) tmp[j] = f2bf(tile[(k8 + j) * 65 + n]);
    *(uint4*)(dst + (size_t)n * 4096 + k8) = *(const uint4*)tmp;
  }
}

// ---------------- m97-style bf16 GEMM: C[M,N] = A[M,4096] * (BT[N,4096])^T ----------------
template<int OUTF32>
__global__ __launch_bounds__(256) void gemm_kernel(const u16* __restrict__ A, const u16* __restrict__ BT,
                                                   void* __restrict__ Cv, int N, int ntn){
  constexpr int K = 4096;
  __shared__ u16 As[2][128 * 32];
  __shared__ u16 Bs[2][128 * 32];
  int bid = blockIdx.x;
  int bm = bid / ntn, bn = bid % ntn;
  int tid = threadIdx.x, lane = tid & 63, w = tid >> 6;
  int wr = w >> 1, wc = w & 1;
  int l15 = lane & 15, lh = lane >> 4;
  const u16* Ab = A  + (size_t)(bm * 128) * K;
  const u16* Bb = BT + (size_t)(bn * 128) * K;
  f32x4 acc[4][4];
  #pragma unroll
  for (int m = 0; m < 4; ++m)
    #pragma unroll
    for (int n = 0; n < 4; ++n) acc[m][n] = f32x4{0.f, 0.f, 0.f, 0.f};

  auto stage = [&](int buf, int k0){
    #pragma unroll
    for (int p = 0; p < 2; ++p){
      int cid = tid + p * 256;
      int row = cid >> 2, k8 = (cid & 3) * 8;
      llds16(Ab + (size_t)row * K + k0 + k8, (char*)(&As[buf][0]) + p * 4096 + w * 1024);
      llds16(Bb + (size_t)row * K + k0 + k8, (char*)(&Bs[buf][0]) + p * 4096 + w * 1024);
    }
  };
  stage(0, 0);
  __syncthreads();
  for (int kt = 0; kt < K / 32; ++kt){
    int cur = kt & 1;
    if (kt + 1 < K / 32) stage(cur ^ 1, (kt + 1) * 32);
    uint4 af[4], bfr[4];
    #pragma unroll
    for (int i = 0; i < 4; ++i){
      af[i]  = *(const uint4*)(&As[cur][(wr * 64 + i * 16 + l15) * 32 + lh * 8]);
      bfr[i] = *(const uint4*)(&Bs[cur][(wc * 64 + i * 16 + l15) * 32 + lh * 8]);
    }
    #pragma unroll
    for (int m = 0; m < 4; ++m)
      #pragma unroll
      for (int n = 0; n < 4; ++n)
        acc[m][n] = __builtin_amdgcn_mfma_f32_16x16x32_bf16(as_bf(af[m]), as_bf(bfr[n]), acc[m][n], 0, 0, 0);
    __syncthreads();
  }
  int row0 = bm * 128 + wr * 64, col0 = bn * 128 + wc * 64;
  if (OUTF32){
    float* C = (float*)Cv;
    #pragma unroll
    for (int m = 0; m < 4; ++m)
      #pragma unroll
      for (int n = 0; n < 4; ++n)
        #pragma unroll
        for (int r = 0; r < 4; ++r)
          C[(size_t)(row0 + m * 16 + lh * 4 + r) * N + col0 + n * 16 + l15] = acc[m][n][r];
  } else {
    u16* C = (u16*)Cv;
    #pragma unroll
    for (int m = 0; m < 4; ++m)
      #pragma unroll
      for (int n = 0; n < 4; ++n)
        #pragma unroll
        for (int r = 0; r < 4; ++r)
          C[(size_t)(row0 + m * 16 + lh * 4 + r) * N + col0 + n * 16 + l15] = f2bf(acc[m][n][r]);
  }
}

// ---------------- RoPE: Q (scaled, swizzled) -> qrope ; K -> knew fp32 ; V copy -> vnew fp32 ----------------
__global__ __launch_bounds__(256) void rope_kernel(const u16* __restrict__ qkvp, u16* __restrict__ qrope,
                                                   float* __restrict__ knew, float* __restrict__ vnew){
  int z = blockIdx.x, tid = threadIdx.x;
  if (z < 512){
    int b = z >> 5, h = z & 31;
    u16* dst = qrope + (size_t)((b * 32 + h) * 64) * 128;
    for (int it = 0; it < 16; ++it){
      int i = tid + it * 256;
      int s = i >> 6, j = i & 63;
      const u16* src = qkvp + (size_t)(b * 64 + s) * 6144 + h * 128;
      float q0 = bf2f(src[j]), q1 = bf2f(src[j + 64]);
      float inv = expf(-(float)j * 0.14391157f);      // 1/10000^(j/64)
      float ang = (4032.0f + (float)s) * inv;
      float sn = sinf(ang), cs = cosf(ang);
      // swizzled store: elem (q=s, d) at q*128 + ((dc&8)|((dc^q)&7))*8 + (d&7)
      int dcs = ((j >> 3) ^ s) & 7;
      dst[s * 128 + dcs * 8 + (j & 7)]      = f2bf((q0 * cs - q1 * sn) * CSC);
      dst[s * 128 + 64 + dcs * 8 + (j & 7)] = f2bf((q1 * cs + q0 * sn) * CSC);
    }
  } else {
    int z2 = z - 512, b = z2 >> 3, kvh = z2 & 7;
    for (int it = 0; it < 16; ++it){
      int i = tid + it * 256;
      int s = i >> 6, j = i & 63;
      const u16* src = qkvp + (size_t)(b * 64 + s) * 6144 + 4096 + kvh * 128;
      float q0 = bf2f(src[j]), q1 = bf2f(src[j + 64]);
      float inv = expf(-(float)j * 0.14391157f);
      float ang = (4032.0f + (float)s) * inv;
      float sn = sinf(ang), cs = cosf(ang);
      float* kd = knew + ((size_t)(b * 8 + kvh) * 64 + s) * 128;
      kd[j]      = q0 * cs - q1 * sn;
      kd[j + 64] = q1 * cs + q0 * sn;
      const u16* vs = qkvp + (size_t)(b * 64 + s) * 6144 + 5120 + kvh * 128;
      float* vd = vnew + ((size_t)(b * 8 + kvh) * 64 + s) * 128;
      vd[j]      = bf2f(vs[j]);
      vd[j + 64] = bf2f(vs[j + 64]);
    }
  }
}

// ---------------- flash attention, fused beam-gather + fp32->bf16, producer-consumer waves ----------------
// block: 512 thr = 4 consumer waves (one head each) + 4 producer waves
// T14: producer double-ring -- ds-write tile it+1 from regs loaded last iter, then issue loads for it+2
__global__ __launch_bounds__(512, 2) void attn_kernel(const u16* __restrict__ qrope, const float* __restrict__ pastk,
                                                      const float* __restrict__ pastv, const float* __restrict__ knew,
                                                      const float* __restrict__ vnew, const int* __restrict__ beam,
                                                      float* __restrict__ pctx, float* __restrict__ pm,
                                                      float* __restrict__ pl){
  __shared__ u16 Qs[4][8192];   // per consumer wave: [64 q][128 d], chunk-swizzled (pre-swizzled in qrope)
  __shared__ u16 Ks[2][4096];   // [buf][32 t][128 d], chunk swz (dc&8)|((dc^t)&7)
  __shared__ u16 Vs[2][4608];   // [buf][128 d][stride 36], t-chunk(8) swz c ^ (((d>>3)^d)&3)
  int kv = blockIdx.x, b = blockIdx.y, chunk = blockIdx.z;
  int tid = threadIdx.x, lane = tid & 63, w = tid >> 6;
  int l15 = lane & 15, lh = lane >> 4;
  constexpr int NT = 32;

  if (w >= 4){
    // ================= producer =================
    int p = w - 4;
    int dblk = l15;               // 8-d block
    int tq = p * 8 + lh * 2;      // tile-local t (even); stages rows tq, tq+1
    int bmb = beam[b];
    const float* kpast = pastk + (size_t)(bmb * 8 + kv) * 4032 * 128;
    const float* vpast = pastv + (size_t)(bmb * 8 + kv) * 4032 * 128;
    const float* knb = knew + (size_t)(b * 8 + kv) * 64 * 128;
    const float* vnb = vnew + (size_t)(b * 8 + kv) * 64 * 128;

    auto loadTile = [&](int tix, float4* rk, float4* rv){
      int tg0 = chunk * 1024 + tix * 32;
      const float *ksrc, *vsrc;
      if (tg0 >= 4032){ ksrc = knb + (size_t)(tg0 - 4032) * 128; vsrc = vnb + (size_t)(tg0 - 4032) * 128; }
      else            { ksrc = kpast + (size_t)tg0 * 128;         vsrc = vpast + (size_t)tg0 * 128; }
      const float* k0 = ksrc + (size_t)tq * 128 + dblk * 8;
      const float* k1 = ksrc + (size_t)(tq + 1) * 128 + dblk * 8;
      const float* v0 = vsrc + (size_t)tq * 128 + dblk * 8;
      const float* v1 = vsrc + (size_t)(tq + 1) * 128 + dblk * 8;
      rk[0] = *(const float4*)k0; rk[1] = *(const float4*)(k0 + 4);
      rk[2] = *(const float4*)k1; rk[3] = *(const float4*)(k1 + 4);
      rv[0] = *(const float4*)v0; rv[1] = *(const float4*)(v0 + 4);
      rv[2] = *(const float4*)v1; rv[3] = *(const float4*)(v1 + 4);
    };
    auto writeTile = [&](int buf, const float4* rk, const float4* rv){
      uint4 pk0, pk1;
      pk0.x = cvtpk(rk[0].x, rk[0].y); pk0.y = cvtpk(rk[0].z, rk[0].w);
      pk0.z = cvtpk(rk[1].x, rk[1].y); pk0.w = cvtpk(rk[1].z, rk[1].w);
      pk1.x = cvtpk(rk[2].x, rk[2].y); pk1.y = cvtpk(rk[2].z, rk[2].w);
      pk1.z = cvtpk(rk[3].x, rk[3].y); pk1.w = cvtpk(rk[3].z, rk[3].w);
      int dcs0 = (dblk & 8) | ((dblk ^ tq) & 7);
      int dcs1 = (dblk & 8) | ((dblk ^ (tq + 1)) & 7);
      *(uint4*)(&Ks[buf][tq * 128 + dcs0 * 8])       = pk0;
      *(uint4*)(&Ks[buf][(tq + 1) * 128 + dcs1 * 8]) = pk1;
      float va[8] = {rv[0].x, rv[0].y, rv[0].z, rv[0].w, rv[1].x, rv[1].y, rv[1].z, rv[1].w};
      float vb[8] = {rv[2].x, rv[2].y, rv[2].z, rv[2].w, rv[3].x, rv[3].y, rv[3].z, rv[3].w};
      #pragma unroll
      for (int dd = 0; dd < 8; ++dd){
        int d = dblk * 8 + dd;
        int cc = (p ^ ((dblk ^ dd) & 3)) & 3;      // chunk=p, swz by ((d>>3)^d)&3
        *(u32*)(&Vs[buf][d * 36 + cc * 8 + lh * 2]) = cvtpk(va[dd], vb[dd]);
      }
    };

    float4 rkA[4], rvA[4], rkB[4], rvB[4];
    loadTile(0, rkA, rvA);
    asm volatile("s_waitcnt vmcnt(0)" ::: "memory");
    writeTile(0, rkA, rvA);
    loadTile(1, rkB, rvB);
    asm volatile("s_waitcnt lgkmcnt(0)" ::: "memory");
    __builtin_amdgcn_sched_barrier(0);
    __builtin_amdgcn_s_barrier();
    __builtin_amdgcn_sched_barrier(0);
    for (int it = 0; it < NT; it += 2){
      // consumer on buf0 (tile it); stage tile it+1 -> buf1 from B; prefetch it+2 -> A
      if (it + 1 < NT){
        asm volatile("s_waitcnt vmcnt(0)" ::: "memory");
        writeTile(1, rkB, rvB);
        if (it + 2 < NT) loadTile(it + 2, rkA, rvA);
        asm volatile("s_waitcnt lgkmcnt(0)" ::: "memory");
      }
      __builtin_amdgcn_sched_barrier(0);
      __builtin_amdgcn_s_barrier();
      __builtin_amdgcn_sched_barrier(0);
      // consumer on buf1 (tile it+1); stage tile it+2 -> buf0 from A; prefetch it+3 -> B
      if (it + 2 < NT){
        asm volatile("s_waitcnt vmcnt(0)" ::: "memory");
        writeTile(0, rkA, rvA);
        if (it + 3 < NT) loadTile(it + 3, rkB, rvB);
        asm volatile("s_waitcnt lgkmcnt(0)" ::: "memory");
      }
      __builtin_amdgcn_sched_barrier(0);
      __builtin_amdgcn_s_barrier();
      __builtin_amdgcn_sched_barrier(0);
    }
    return;
  }

  // ================= consumer =================
  // stage own Q (pre-swizzled in qrope -> linear copy keeps swizzle)
  const u16* qb = qrope + (size_t)((b * 32 + kv * 4 + w) * 64) * 128;
  #pragma unroll
  for (int c = 0; c < 16; ++c)
    llds16((const char*)qb + c * 1024 + lane * 16, (char*)(&Qs[w][0]) + c * 1024);
  asm volatile("s_waitcnt vmcnt(0)" ::: "memory");

  f32x4 cacc[8][4];             // [nd][qm]: ctx^T rows d=nd*16+lh*4+r, cols q=qm*16+l15
  float mrow[4], lrow[4];
  #pragma unroll
  for (int qm = 0; qm < 4; ++qm){ mrow[qm] = -3.0e38f; lrow[qm] = 0.f; }
  #pragma unroll
  for (int nd = 0; nd < 8; ++nd)
    #pragma unroll
    for (int qm = 0; qm < 4; ++qm) cacc[nd][qm] = f32x4{0.f, 0.f, 0.f, 0.f};

  __builtin_amdgcn_sched_barrier(0);
  __builtin_amdgcn_s_barrier();
  __builtin_amdgcn_sched_barrier(0);

  for (int it = 0; it < NT; ++it){
    const u16* Kc = &Ks[it & 1][0];
    const u16* Vc = &Vs[it & 1][0];

    // S^T = K * Q^T : sacc[tt][qm] rows t=tt*16+lh*4+r, cols q=qm*16+l15
    f32x4 sacc[2][4];
    #pragma unroll
    for (int tt = 0; tt < 2; ++tt)
      #pragma unroll
      for (int qm = 0; qm < 4; ++qm) sacc[tt][qm] = f32x4{0.f, 0.f, 0.f, 0.f};
    #pragma unroll
    for (int ks = 0; ks < 4; ++ks){
      int dc = ks * 4 + lh;
      int dcs = (dc & 8) | ((dc ^ l15) & 7);
      uint4 kf0 = *(const uint4*)(Kc + l15 * 128 + dcs * 8);
      uint4 kf1 = *(const uint4*)(Kc + (16 + l15) * 128 + dcs * 8);
      #pragma unroll
      for (int qm = 0; qm < 4; ++qm){
        uint4 qf = *(const uint4*)(&Qs[w][(qm * 16 + l15) * 128 + dcs * 8]);
        sacc[0][qm] = __builtin_amdgcn_mfma_f32_16x16x32_bf16(as_bf(kf0), as_bf(qf), sacc[0][qm], 0, 0, 0);
        sacc[1][qm] = __builtin_amdgcn_mfma_f32_16x16x32_bf16(as_bf(kf1), as_bf(qf), sacc[1][qm], 0, 0, 0);
      }
    }

    // causal mask: only last two tiles of chunk 3 (new tokens)
    if (chunk == 3 && it >= 30){
      int toff = (it - 30) * 32;
      #pragma unroll
      for (int tt = 0; tt < 2; ++tt)
        #pragma unroll
        for (int qm = 0; qm < 4; ++qm)
          #pragma unroll
          for (int r = 0; r < 4; ++r){
            int t = toff + tt * 16 + lh * 4 + r;
            int q = qm * 16 + l15;
            if (t > q) sacc[tt][qm][r] = -3.0e38f;
          }
    }

    // lazy online softmax: lane-local max check; full reduce+rescale only on trigger;
    // l kept as lane-local partial (sum is linear) and reduced once after the loop.
    #pragma unroll
    for (int qm = 0; qm < 4; ++qm){
      float rm = sacc[0][qm][0];
      #pragma unroll
      for (int tt = 0; tt < 2; ++tt)
        #pragma unroll
        for (int r = 0; r < 4; ++r) rm = fmaxf(rm, sacc[tt][qm][r]);
      if (__any(rm > mrow[qm] + 8.0f)){          // defer-max (log2 units)
        rm = fmaxf(rm, __shfl_xor(rm, 16));
        rm = fmaxf(rm, __shfl_xor(rm, 32));
        float mn = fmaxf(mrow[qm], rm);
        float esc = exp2f(mrow[qm] - mn);
        mrow[qm] = mn;
        lrow[qm] *= esc;
        #pragma unroll
        for (int nd = 0; nd < 8; ++nd) cacc[nd][qm] *= esc;
      }
      float s = 0.f;
      #pragma unroll
      for (int tt = 0; tt < 2; ++tt)
        #pragma unroll
        for (int r = 0; r < 4; ++r){
          float pp = exp2f(sacc[tt][qm][r] - mrow[qm]);
          sacc[tt][qm][r] = pp;
          s += pp;
        }
      lrow[qm] += s;                             // lane-local partial
    }

    // ctx^T += V^T * P^T via 16x16x16 MFMA (P in registers)
    #pragma unroll
    for (int tt = 0; tt < 2; ++tt){
      s16x4 pa[4];
      #pragma unroll
      for (int qm = 0; qm < 4; ++qm){
        uint2 u;
        u.x = cvtpk(sacc[tt][qm][0], sacc[tt][qm][1]);
        u.y = cvtpk(sacc[tt][qm][2], sacc[tt][qm][3]);
        pa[qm] = __builtin_bit_cast(s16x4, u);
      }
      #pragma unroll
      for (int nd = 0; nd < 8; ++nd){
        int swzv = ((nd * 2) ^ (l15 >> 3) ^ l15) & 3;          // ((d>>3)^d)&3
        int cc = ((tt * 2 + (lh >> 1)) ^ swzv) & 3;
        uint2 vr = *(const uint2*)(Vc + (nd * 16 + l15) * 36 + cc * 8 + (lh & 1) * 4);
        s16x4 vfr = __builtin_bit_cast(s16x4, vr);
        #pragma unroll
        for (int qm = 0; qm < 4; ++qm)
          cacc[nd][qm] = mfma16(vfr, pa[qm], cacc[nd][qm]);
      }
    }
    __builtin_amdgcn_sched_barrier(0);
    __builtin_amdgcn_s_barrier();
    __builtin_amdgcn_sched_barrier(0);
  }

  // reduce lane-local l partials across the 4 lh replicas of each q
  #pragma unroll
  for (int qm = 0; qm < 4; ++qm){
    lrow[qm] += __shfl_xor(lrow[qm], 16);
    lrow[qm] += __shfl_xor(lrow[qm], 32);
  }

  // unnormalized partials (contiguous stores) + (m,l)
  float* pc = pctx + (size_t)(((chunk * 16 + b) * 8 + kv) * 4 + w) * 8192;
  #pragma unroll
  for (int qm = 0; qm < 4; ++qm){
    int q = qm * 16 + l15;
    #pragma unroll
    for (int nd = 0; nd < 8; ++nd)
      *(f32x4*)(pc + (size_t)q * 128 + nd * 16 + lh * 4) = cacc[nd][qm];
  }
  if (lh == 0){
    size_t mb = (size_t)((chunk * 16 + b) * 8 + kv) * 256 + w * 64;
    #pragma unroll
    for (int qm = 0; qm < 4; ++qm){
      pm[mb + qm * 16 + l15] = mrow[qm];
      pl[mb + qm * 16 + l15] = lrow[qm];
    }
  }
}

// ---------------- combine the 4 chunk partials ----------------
__global__ __launch_bounds__(256) void combine_kernel(const float* __restrict__ pctx, const float* __restrict__ pm,
                                                      const float* __restrict__ pl, u16* __restrict__ ctxb){
  int z = blockIdx.x;
  int g = z & 3, kv = (z >> 2) & 7, b = z >> 5;
  int tid = threadIdx.x;
  int s = tid >> 2, dq = (tid & 3) * 32;
  float mv[4], lv[4];
  #pragma unroll
  for (int c = 0; c < 4; ++c){
    size_t mi = (size_t)((c * 16 + b) * 8 + kv) * 256 + g * 64 + s;
    mv[c] = pm[mi]; lv[c] = pl[mi];
  }
  float M = fmaxf(fmaxf(mv[0], mv[1]), fmaxf(mv[2], mv[3]));
  float wc[4], wsum = 0.f;
  #pragma unroll
  for (int c = 0; c < 4; ++c){ wc[c] = exp2f(mv[c] - M); wsum += wc[c] * lv[c]; }
  float inv = 1.0f / wsum;
  u16* dst = ctxb + (size_t)(b * 64 + s) * 4096 + (kv * 4 + g) * 128 + dq;
  #pragma unroll
  for (int j4 = 0; j4 < 8; ++j4){
    float4 a = {0.f, 0.f, 0.f, 0.f};
    #pragma unroll
    for (int c = 0; c < 4; ++c){
      const float* p = pctx + (size_t)(((c * 16 + b) * 8 + kv) * 4 + g) * 8192 + s * 128 + dq + j4 * 4;
      float4 v = *(const float4*)p;
      a.x += wc[c] * v.x; a.y += wc[c] * v.y; a.z += wc[c] * v.z; a.w += wc[c] * v.w;
    }
    u16 t4[4] = {f2bf(a.x * inv), f2bf(a.y * inv), f2bf(a.z * inv), f2bf(a.w * inv)};
    *(uint2*)(dst + j4 * 4) = *(const uint2*)t4;
  }
}

extern "C" void kernel_launch(void* const* d_in, const int* in_sizes, int n_in,
                              void* d_out, int out_size, void* d_ws, size_t ws_size,
                              hipStream_t stream){
  const float* hidden = (const float*)d_in[0];
  const float* pastk  = (const float*)d_in[1];
  const float* pastv  = (const float*)d_in[2];
  const float* qw     = (const float*)d_in[3];
  const float* kw     = (const float*)d_in[4];
  const float* vw     = (const float*)d_in[5];
  const float* ow     = (const float*)d_in[6];
  const int*   beam   = (const int*)d_in[7];

  char* ws = (char*)d_ws;
  size_t off = 0;
  auto alloc = [&](size_t sz){ char* p = ws + off; off += sz; return p; };
  u16*   wtall = (u16*)alloc(50331648);     // [6144][4096] bf16: q,k,v weights transposed
  u16*   wto   = (u16*)alloc(33554432);     // [4096][4096] bf16: out_wei transposed
  u16*   hidb  = (u16*)alloc(8388608);      // hidden bf16 [1024][4096]
  u16*   qkvp  = (u16*)alloc(12582912);     // QKV proj [1024][6144]
  u16*   qrope = (u16*)alloc(8388608);      // [16][32][64][128] swizzled
  float* knew  = (float*)alloc(4194304);    // [16][8][64][128] fp32 roped new K
  float* vnew  = (float*)alloc(4194304);    // [16][8][64][128] fp32 new V
  float* pctx  = (float*)alloc(67108864);   // [4][16][8][4][64][128]
  float* pm    = (float*)alloc(524288);
  float* pl    = (float*)alloc(524288);
  u16*   ctxb  = (u16*)alloc(8388608);      // [1024][4096]
  if (off > ws_size) return;                // workspace too small -> fail loudly

  cvt_hid_kernel<<<2048, 256, 0, stream>>>(hidden, hidb);
  wtrans_kernel<<<10240, 256, 0, stream>>>(qw, kw, vw, ow, wtall, wto);
  gemm_kernel<0><<<384, 256, 0, stream>>>(hidb, wtall, (void*)qkvp, 6144, 48);
  rope_kernel<<<640, 256, 0, stream>>>(qkvp, qrope, knew, vnew);
  attn_kernel<<<dim3(8, 16, 4), 512, 0, stream>>>(qrope, pastk, pastv, knew, vnew, beam, pctx, pm, pl);
  combine_kernel<<<512, 256, 0, stream>>>(pctx, pm, pl, ctxb);
  gemm_kernel<1><<<256, 256, 0, stream>>>(ctxb, wto, d_out, 4096, 32);
}